// Round 1
// baseline (911.229 us; speedup 1.0000x reference)
//
#include <hip/hip_runtime.h>

// ---------------- problem constants ----------------
#define BQ   8
#define SQ   1569
#define BS   12552      // BQ*SQ
#define DM   768
#define NH   12
#define DH   64
#define TT   8
#define PP   196
#define D4   3072
#define QKVN 2304
#define CCH  24         // CLS split-K chunks
#define CKEY 66         // keys per chunk (24*66 = 1584 >= 1569)
#define MB_PAD 104      // 99 m-blocks padded to multiple of 8 for XCD-stable swizzle
#define MB256 50        // ceil(12552/256) for the 256-tile kernel

typedef _Float16 f16;
typedef _Float16 f16x8 __attribute__((ext_vector_type(8)));
typedef float    f32x4 __attribute__((ext_vector_type(4)));
typedef unsigned long long u64;

#define AS1 __attribute__((address_space(1)))
#define AS3 __attribute__((address_space(3)))

#define Y_OFF    0ULL
#define QKV_OFF  19279872ULL
#define CTX_OFF  77119488ULL
#define H_OFF    19279872ULL
#define W_OFF    96399360ULL

// ---------------- LayerNorm (wave per row) ----------------
__global__ __launch_bounds__(256) void ln_kernel(const float* __restrict__ x,
                                                 const float* __restrict__ g,
                                                 const float* __restrict__ bta,
                                                 f16* __restrict__ y) {
    int row = blockIdx.x * 4 + (threadIdx.x >> 6);
    int lane = threadIdx.x & 63;
    if (row >= BS) return;
    const float* xr = x + (u64)row * DM;
    float v[12];
    float s = 0.f, s2 = 0.f;
#pragma unroll
    for (int i = 0; i < 12; i++) { v[i] = xr[lane + i * 64]; s += v[i]; s2 += v[i] * v[i]; }
#pragma unroll
    for (int m = 1; m < 64; m <<= 1) { s += __shfl_xor(s, m, 64); s2 += __shfl_xor(s2, m, 64); }
    float mean = s * (1.f / 768.f);
    float var  = s2 * (1.f / 768.f) - mean * mean;
    float rstd = rsqrtf(var + 1e-12f);
    f16* yr = y + (u64)row * DM;
#pragma unroll
    for (int i = 0; i < 12; i++) {
        int c = lane + i * 64;
        yr[c] = (f16)((v[i] - mean) * rstd * g[c] + bta[c]);
    }
}

// ---------------- transpose fp32 -> f16 (dst[c*R+r] = src[r*C+c]) ----------------
__global__ __launch_bounds__(256) void transpose_kernel(const float* __restrict__ src,
                                                        f16* __restrict__ dst,
                                                        int R, int C) {
    __shared__ float tile[32][33];
    int bx = blockIdx.x * 32;
    int by = blockIdx.y * 32;
    int tx = threadIdx.x & 31, ty = threadIdx.x >> 5;
#pragma unroll
    for (int i = 0; i < 4; i++) {
        int r = by + ty + i * 8, c = bx + tx;
        if (r < R && c < C) tile[ty + i * 8][tx] = src[(u64)r * C + c];
    }
    __syncthreads();
#pragma unroll
    for (int i = 0; i < 4; i++) {
        int c = bx + ty + i * 8, r = by + tx;
        if (c < C && r < R) dst[(u64)c * R + r] = (f16)tile[tx][ty + i * 8];
    }
}

// ---------------- concat 3 bias vectors (768 each) ----------------
__global__ __launch_bounds__(256) void bias3_kernel(const float* __restrict__ a,
                                                    const float* __restrict__ b,
                                                    const float* __restrict__ c,
                                                    float* __restrict__ dst) {
    int i = blockIdx.x * 256 + threadIdx.x;
    if (i < 768) { dst[i] = a[i]; dst[i + 768] = b[i]; dst[i + 1536] = c[i]; }
}

// ---------------- GEMM v5 (kept for N=768 outputs): R4 staging + 1-barrier dbuf ----------------
template <int NOUT, bool GELU, bool RESID, bool OUTF16>
__global__ __launch_bounds__(256, 4) void gemm_kernel(const f16* __restrict__ A,
                                                      const f16* __restrict__ Bt,
                                                      const float* __restrict__ bias,
                                                      const float* __restrict__ resid,
                                                      float* __restrict__ Cf,
                                                      f16* __restrict__ Ch,
                                                      int K) {
    __shared__ __align__(16) f16 As[2][128 * 32];
    __shared__ __align__(16) f16 Bs[2][128 * 32];
    int id = blockIdx.x;
    int mb = id % MB_PAD, nb = id / MB_PAD;
    if (mb >= 99) return;
    int tid  = threadIdx.x;
    int lane = tid & 63, wave = tid >> 6;
    int wm = wave >> 1, wn = wave & 1;
    int m0 = mb * 128, n0 = nb * 128;
    int l15 = lane & 15, quad = lane >> 4;

    int r0   = wave * 16 + (lane >> 2);
    int coff = (lane & 3) * 8;
    const f16* ag0 = A + (u64)(m0 + r0) * K + coff;
    const f16* ag1 = A + (u64)(m0 + r0 + 64) * K + coff;
    bool av0 = (m0 + r0) < BS, av1 = (m0 + r0 + 64) < BS;
    const f16* bg0 = Bt + (u64)(n0 + r0) * K + coff;
    const f16* bg1 = Bt + (u64)(n0 + r0 + 64) * K + coff;
    int lofs = wave * 1024;

    f32x4 acc[4][4];
#pragma unroll
    for (int i = 0; i < 4; i++)
#pragma unroll
        for (int j = 0; j < 4; j++)
#pragma unroll
            for (int r = 0; r < 4; r++) acc[i][j][r] = 0.f;

    if (av0) __builtin_amdgcn_global_load_lds((const AS1 void*)ag0, (AS3 void*)((AS3 char*)&As[0][0] + lofs), 16, 0, 0);
    if (av1) __builtin_amdgcn_global_load_lds((const AS1 void*)ag1, (AS3 void*)((AS3 char*)&As[0][0] + lofs + 4096), 16, 0, 0);
    __builtin_amdgcn_global_load_lds((const AS1 void*)bg0, (AS3 void*)((AS3 char*)&Bs[0][0] + lofs), 16, 0, 0);
    __builtin_amdgcn_global_load_lds((const AS1 void*)bg1, (AS3 void*)((AS3 char*)&Bs[0][0] + lofs + 4096), 16, 0, 0);
    ag0 += 32; ag1 += 32; bg0 += 32; bg1 += 32;

    int nit = K >> 5;
    for (int it = 0; it < nit; it++) {
        __syncthreads();
        int buf = it & 1;
        if (it + 1 < nit) {
            int nb2 = buf ^ 1;
            if (av0) __builtin_amdgcn_global_load_lds((const AS1 void*)ag0, (AS3 void*)((AS3 char*)&As[nb2][0] + lofs), 16, 0, 0);
            if (av1) __builtin_amdgcn_global_load_lds((const AS1 void*)ag1, (AS3 void*)((AS3 char*)&As[nb2][0] + lofs + 4096), 16, 0, 0);
            __builtin_amdgcn_global_load_lds((const AS1 void*)bg0, (AS3 void*)((AS3 char*)&Bs[nb2][0] + lofs), 16, 0, 0);
            __builtin_amdgcn_global_load_lds((const AS1 void*)bg1, (AS3 void*)((AS3 char*)&Bs[nb2][0] + lofs + 4096), 16, 0, 0);
            ag0 += 32; ag1 += 32; bg0 += 32; bg1 += 32;
        }
        f16x8 af[4], bf[4];
#pragma unroll
        for (int i = 0; i < 4; i++)
            af[i] = *(const f16x8*)(&As[buf][(wm * 64 + i * 16 + l15) * 32 + quad * 8]);
#pragma unroll
        for (int j = 0; j < 4; j++)
            bf[j] = *(const f16x8*)(&Bs[buf][(wn * 64 + j * 16 + l15) * 32 + quad * 8]);
#pragma unroll
        for (int i = 0; i < 4; i++)
#pragma unroll
            for (int j = 0; j < 4; j++)
                acc[i][j] = __builtin_amdgcn_mfma_f32_16x16x32_f16(af[i], bf[j], acc[i][j], 0, 0, 0);
    }

#pragma unroll
    for (int i = 0; i < 4; i++) {
#pragma unroll
        for (int j = 0; j < 4; j++) {
            int col = n0 + wn * 64 + j * 16 + l15;
            float bv = bias[col];
#pragma unroll
            for (int r = 0; r < 4; r++) {
                int row = m0 + wm * 64 + i * 16 + quad * 4 + r;
                if (row < BS) {
                    float v = acc[i][j][r] + bv;
                    if (GELU) {
                        float u = 0.7978845608028654f * (v + 0.044715f * v * v * v);
                        float e = __builtin_exp2f(-2.885390081777927f * u);
                        v = v / (1.f + e);
                    }
                    if (RESID) v += resid[(u64)row * NOUT + col];
                    if (OUTF16) Ch[(u64)row * NOUT + col] = (f16)v;
                    else        Cf[(u64)row * NOUT + col] = v;
                }
            }
        }
    }
}

// ---------------- GEMM v6: 256x256 8-phase pipeline (HK-style), f16 out ----------------
// C = A(BS x K, f16) @ Bt^T (Bt: N x K, f16) + bias [+gelu], f16 out.
// 512 threads = 8 waves; per phase one 128x128 C-quadrant (qm,qn), each wave a 64x32
// patch (pm,pn) = 16 MFMA x K=64. LDS 128 KB: 2 buf x {A,B} x [256][64] f16,
// granule XOR swizzle (g ^= row&7): inverse-swizzled GLOBAL source for
// global_load_lds (linear LDS dest) + swizzled ds_read -> conflict-free b128 reads.
// Staging: 1 half-tile (128x64) per phase into the region freed one phase earlier:
//   P1: A1(kt+1)  P2: B0(kt+1)  P3: A0(kt+2)  P4: B1(kt+2)
// Counted s_waitcnt vmcnt(4) once per K-tile (P4) keeps 2 half-tiles in flight
// across barriers (drain 0 at the tail). Raw s_barrier, setprio(1) around MFMA.
// M-tail rows are CLAMPED (not skipped) in staging so per-wave vmcnt counts stay
// uniform; epilogue masks row >= BS.
template <int NOUT, bool GELU>
__global__ __launch_bounds__(512, 2) void gemm256_kernel(const f16* __restrict__ A,
                                                         const f16* __restrict__ Bt,
                                                         const float* __restrict__ bias,
                                                         f16* __restrict__ Ch,
                                                         int K) {
    __shared__ __align__(16) f16 lds[2][2][16384];
    int id = blockIdx.x;
    int mb = id % MB256, nb = id / MB256;
    int m0 = mb * 256, n0 = nb * 256;
    int tid = threadIdx.x;
    int lane = tid & 63, wave = tid >> 6;
    int pm = wave >> 2, pn = wave & 3;
    int l15 = lane & 15, quad = lane >> 4;
    int s7 = l15 & 7;
    int g0 = (quad ^ s7) << 4;           // byte offset of swizzled granule, kk=0
    int g1 = ((quad ^ s7) ^ 4) << 4;     // kk=1
    int rbA = (pm * 64 + l15) * 128;     // byte row base within A tile (qm=0)
    int rbB = (pn * 32 + l15) * 128;

    // staging: thread covers LDS bytes q*8192 + wave*1024 + lane*16 of a half-tile
    // => row = q*64 + wave*8 + (lane>>3), lds granule = lane&7,
    //    global granule = (lane&7) ^ (row&7) = (lane&7) ^ (lane>>3)
    int srow8 = (wave << 3) + (lane >> 3);
    u64 sgel = (u64)(((lane & 7) ^ (lane >> 3)) << 3);
    u64 offA[4], offB[4];                // element offsets per (half,q)
#pragma unroll
    for (int i = 0; i < 4; i++) {
        int ra = m0 + i * 64 + srow8; if (ra > BS - 1) ra = BS - 1;   // clamp M tail
        offA[i] = (u64)ra * K + sgel;
        offB[i] = (u64)(n0 + i * 64 + srow8) * K + sgel;
    }

#define STAGE_A(BUF, HALF, KT) { \
    AS3 char* _d = (AS3 char*)&lds[BUF][0][0] + (HALF) * 16384 + wave * 1024; \
    __builtin_amdgcn_global_load_lds((const AS1 void*)(A + offA[(HALF) * 2]     + (u64)(KT) * 64), (AS3 void*)_d, 16, 0, 0); \
    __builtin_amdgcn_global_load_lds((const AS1 void*)(A + offA[(HALF) * 2 + 1] + (u64)(KT) * 64), (AS3 void*)(_d + 8192), 16, 0, 0); \
}
#define STAGE_B(BUF, HALF, KT) { \
    AS3 char* _d = (AS3 char*)&lds[BUF][1][0] + (HALF) * 16384 + wave * 1024; \
    __builtin_amdgcn_global_load_lds((const AS1 void*)(Bt + offB[(HALF) * 2]     + (u64)(KT) * 64), (AS3 void*)_d, 16, 0, 0); \
    __builtin_amdgcn_global_load_lds((const AS1 void*)(Bt + offB[(HALF) * 2 + 1] + (u64)(KT) * 64), (AS3 void*)(_d + 8192), 16, 0, 0); \
}
#define PH_READ_A(QM) { \
    _Pragma("unroll") for (int im = 0; im < 4; im++) { \
        af[im][0] = *(const f16x8*)(Ap + (QM) * 16384 + rbA + im * 2048 + g0); \
        af[im][1] = *(const f16x8*)(Ap + (QM) * 16384 + rbA + im * 2048 + g1); \
    } }
#define PH_READ_B(QN) { \
    _Pragma("unroll") for (int jn = 0; jn < 2; jn++) { \
        bf[jn][0] = *(const f16x8*)(Bp + (QN) * 16384 + rbB + jn * 2048 + g0); \
        bf[jn][1] = *(const f16x8*)(Bp + (QN) * 16384 + rbB + jn * 2048 + g1); \
    } }
#define PH_MMA(QM, QN) { \
    __builtin_amdgcn_s_setprio(1); \
    _Pragma("unroll") for (int im = 0; im < 4; im++) \
    _Pragma("unroll") for (int jn = 0; jn < 2; jn++) { \
        acc[QM][QN][im][jn] = __builtin_amdgcn_mfma_f32_16x16x32_f16(af[im][0], bf[jn][0], acc[QM][QN][im][jn], 0, 0, 0); \
        acc[QM][QN][im][jn] = __builtin_amdgcn_mfma_f32_16x16x32_f16(af[im][1], bf[jn][1], acc[QM][QN][im][jn], 0, 0, 0); \
    } \
    __builtin_amdgcn_s_setprio(0); \
}

    f32x4 acc[2][2][4][2];
#pragma unroll
    for (int a = 0; a < 2; a++)
#pragma unroll
        for (int b = 0; b < 2; b++)
#pragma unroll
            for (int c = 0; c < 4; c++)
#pragma unroll
                for (int d = 0; d < 2; d++)
#pragma unroll
                    for (int r = 0; r < 4; r++) acc[a][b][c][d][r] = 0.f;
    f16x8 af[4][2], bf[2][2];

    int nk = K >> 6;   // K-tiles of 64 (requires nk >= 2; K=768 -> 12)
    // prologue: tile 0 complete + tile 1's A0,B1 (the "(k-1).P3/P4" slots for k=0)
    STAGE_A(0, 0, 0); STAGE_B(0, 0, 0); STAGE_A(0, 1, 0); STAGE_B(0, 1, 0);
    STAGE_A(1, 0, 1); STAGE_B(1, 1, 1);
    asm volatile("s_waitcnt vmcnt(4)");   // tile 0's 8 loads landed, 4 in flight
    __builtin_amdgcn_s_barrier();

    for (int kt = 0; kt < nk; kt++) {
        int buf = kt & 1, bufn = buf ^ 1;
        const char* Ap = (const char*)&lds[buf][0][0];
        const char* Bp = (const char*)&lds[buf][1][0];
        bool s1 = (kt + 1 < nk), s2 = (kt + 2 < nk);
        // P1: quadrant (0,0); stage A1(kt+1) (A1 of bufn free since (kt-1).P4)
        PH_READ_A(0); PH_READ_B(0);
        if (s1) STAGE_A(bufn, 1, kt + 1);
        __builtin_amdgcn_s_barrier();
        asm volatile("s_waitcnt lgkmcnt(0)");
        PH_MMA(0, 0);
        __builtin_amdgcn_s_barrier();
        // P2: quadrant (0,1); stage B0(kt+1) (B0 of bufn free since (kt-1).P4)
        PH_READ_B(1);
        if (s1) STAGE_B(bufn, 0, kt + 1);
        __builtin_amdgcn_s_barrier();
        asm volatile("s_waitcnt lgkmcnt(0)");
        PH_MMA(0, 1);
        __builtin_amdgcn_s_barrier();
        // P3: quadrant (1,1); stage A0(kt+2) (A0 of buf last read in P2)
        PH_READ_A(1);
        if (s2) STAGE_A(buf, 0, kt + 2);
        __builtin_amdgcn_s_barrier();
        asm volatile("s_waitcnt lgkmcnt(0)");
        PH_MMA(1, 1);
        __builtin_amdgcn_s_barrier();
        // P4: quadrant (1,0); stage B1(kt+2) (B1 of buf last read in P3).
        // Counted wait: allow P3+P4's 4 loads in flight; forces tile kt+1's
        // A1/B0 (P1/P2) and A0/B1 ((kt-1).P3/P4) landed. Drain at the tail.
        PH_READ_B(0);
        if (s2) STAGE_B(buf, 1, kt + 2);
        if (s2) { asm volatile("s_waitcnt vmcnt(4)"); }
        else    { asm volatile("s_waitcnt vmcnt(0)"); }
        __builtin_amdgcn_s_barrier();
        asm volatile("s_waitcnt lgkmcnt(0)");
        PH_MMA(1, 0);
        __builtin_amdgcn_s_barrier();
    }

    // epilogue: C[row = m0+qm*128+pm*64+im*16+quad*4+r][col = n0+qn*128+pn*32+jn*16+l15]
    int quad4 = quad << 2;
#pragma unroll
    for (int qn = 0; qn < 2; qn++)
#pragma unroll
        for (int jn = 0; jn < 2; jn++) {
            int col = n0 + qn * 128 + pn * 32 + jn * 16 + l15;
            float bv = bias[col];
#pragma unroll
            for (int qm = 0; qm < 2; qm++)
#pragma unroll
                for (int im = 0; im < 4; im++) {
                    int rowb = m0 + qm * 128 + pm * 64 + im * 16 + quad4;
#pragma unroll
                    for (int r = 0; r < 4; r++) {
                        int row = rowb + r;
                        if (row < BS) {
                            float v = acc[qm][qn][im][jn][r] + bv;
                            if (GELU) {
                                float u = 0.7978845608028654f * (v + 0.044715f * v * v * v);
                                float e = __builtin_exp2f(-2.885390081777927f * u);
                                v = v / (1.f + e);
                            }
                            Ch[(u64)row * NOUT + col] = (f16)v;
                        }
                    }
                }
        }
#undef STAGE_A
#undef STAGE_B
#undef PH_READ_A
#undef PH_READ_B
#undef PH_MMA
}

// ---------------- time attention: wave per (b,h,p); 8 queries x 9 keys ----------------
__global__ __launch_bounds__(256) void time_attn_kernel(const f16* __restrict__ qkv,
                                                        f16* __restrict__ ctx) {
    int w = blockIdx.x * 4 + (threadIdx.x >> 6);
    int lane = threadIdx.x & 63;
    int b = w / (NH * PP);
    int rem = w % (NH * PP);
    int h = rem / PP, p = rem % PP;
    u64 bb = (u64)b * SQ;
    int hoff = h * 64 + lane;

    float qv[TT], kv[9], vv[9];
#pragma unroll
    for (int t = 0; t < TT; t++) qv[t] = (float)qkv[(bb + 1 + t * PP + p) * QKVN + hoff];
    kv[0] = (float)qkv[bb * QKVN + 768 + hoff];
    vv[0] = (float)qkv[bb * QKVN + 1536 + hoff];
#pragma unroll
    for (int j = 1; j <= TT; j++) {
        u64 ro = (bb + 1 + (u64)(j - 1) * PP + p) * QKVN;
        kv[j] = (float)qkv[ro + 768 + hoff];
        vv[j] = (float)qkv[ro + 1536 + hoff];
    }
#pragma unroll
    for (int t = 0; t < TT; t++) {
        float s[9];
#pragma unroll
        for (int j = 0; j < 9; j++) {
            float ps = qv[t] * kv[j];
#pragma unroll
            for (int m = 1; m < 64; m <<= 1) ps += __shfl_xor(ps, m, 64);
            s[j] = ps * 0.125f;
        }
        float mx = s[0];
#pragma unroll
        for (int j = 1; j < 9; j++) mx = fmaxf(mx, s[j]);
        float sum = 0.f;
#pragma unroll
        for (int j = 0; j < 9; j++) { s[j] = expf(s[j] - mx); sum += s[j]; }
        float o = 0.f;
#pragma unroll
        for (int j = 0; j < 9; j++) o += s[j] * vv[j];
        o /= sum;
        ctx[(bb + 1 + (u64)t * PP + p) * DM + h * 64 + lane] = (f16)o;
    }
}

// ---------------- CLS attention split-K: part kernel, block per (b,h,chunk) ----------------
__global__ __launch_bounds__(256) void cls_part_kernel(const f16* __restrict__ qkv,
                                                       float* __restrict__ part) {
    int g = blockIdx.x;
    int c = g % CCH, bh = g / CCH;
    int b = bh / NH, h = bh % NH;
    u64 bb = (u64)b * SQ;
    int tid = threadIdx.x, lane = tid & 63, wave = tid >> 6;
    __shared__ float sc[CKEY];
    __shared__ float accbuf[4][64];
    __shared__ float lbuf[4];
    __shared__ float mxs;
    float qd = (float)qkv[bb * QKVN + h * 64 + lane];
    int j0 = c * CKEY;
    int cnt = SQ - j0; if (cnt > CKEY) cnt = CKEY;
    for (int jj = wave; jj < cnt; jj += 4) {
        float p = qd * (float)qkv[(bb + j0 + jj) * QKVN + 768 + h * 64 + lane];
#pragma unroll
        for (int m = 1; m < 64; m <<= 1) p += __shfl_xor(p, m, 64);
        if (lane == 0) sc[jj] = p * 0.125f;
    }
    __syncthreads();
    if (wave == 0) {
        float m = -1e30f;
        for (int j = lane; j < cnt; j += 64) m = fmaxf(m, sc[j]);
#pragma unroll
        for (int s = 1; s < 64; s <<= 1) m = fmaxf(m, __shfl_xor(m, s, 64));
        if (lane == 0) mxs = m;
    }
    __syncthreads();
    float mx = mxs;
    float acc = 0.f, l = 0.f;
    for (int jj = wave; jj < cnt; jj += 4) {
        float w = expf(sc[jj] - mx);
        l += w;
        acc += w * (float)qkv[(bb + j0 + jj) * QKVN + 1536 + h * 64 + lane];
    }
    accbuf[wave][lane] = acc;
    if (lane == 0) lbuf[wave] = l;
    __syncthreads();
    if (tid < 64) {
        float a = accbuf[0][tid] + accbuf[1][tid] + accbuf[2][tid] + accbuf[3][tid];
        float* pb = part + ((u64)bh * CCH + c) * 66;
        if (tid == 0) { pb[0] = mxs; pb[1] = lbuf[0] + lbuf[1] + lbuf[2] + lbuf[3]; }
        pb[2 + tid] = a;
    }
}

// ---------------- CLS attention split-K: combine kernel, wave per (b,h) ----------------
__global__ __launch_bounds__(256) void cls_comb_kernel(const float* __restrict__ part,
                                                       f16* __restrict__ ctx) {
    int w = blockIdx.x * 4 + (threadIdx.x >> 6);
    int lane = threadIdx.x & 63;
    if (w >= BQ * NH) return;
    int b = w / NH, h = w % NH;
    const float* pb = part + (u64)w * CCH * 66;
    float m = (lane < CCH) ? pb[lane * 66] : -1e30f;
#pragma unroll
    for (int s = 1; s < 64; s <<= 1) m = fmaxf(m, __shfl_xor(m, s, 64));
    float l = (lane < CCH) ? pb[lane * 66 + 1] * expf(pb[lane * 66] - m) : 0.f;
#pragma unroll
    for (int s = 1; s < 64; s <<= 1) l += __shfl_xor(l, s, 64);
    float o = 0.f;
    for (int j = 0; j < CCH; j++) {
        float mj = pb[j * 66];
        o += pb[j * 66 + 2 + lane] * expf(mj - m);
    }
    ctx[((u64)b * SQ) * DM + h * 64 + lane] = (f16)(o / l);
}

// ---------------- space attention: MFMA flash, block per (b,h,t) ----------------
__global__ __launch_bounds__(256) void space_attn_kernel(const f16* __restrict__ qkv,
                                                         f16* __restrict__ ctx) {
    int g = blockIdx.x;
    int b = g / (NH * TT);
    int rem = g % (NH * TT);
    int h = rem / TT, t = rem % TT;
    __shared__ __align__(16) f16 Vt[64 * 232];
    __shared__ __align__(16) f16 Ps[4 * 16 * 232];
    u64 bb = (u64)b * SQ;
    int tid = threadIdx.x, lane = tid & 63, wave = tid >> 6;
    int l15 = lane & 15, quad = lane >> 4;

    for (int i = tid; i < 4 * 16 * 232 * 2 / 16; i += 256)
        ((uint4*)Ps)[i] = make_uint4(0u, 0u, 0u, 0u);

    for (int idx = tid; idx < 232 * 8; idx += 256) {
        int c8 = idx / 232;
        int j  = idx - c8 * 232;
        int c  = c8 * 8;
        uint4 vraw = make_uint4(0u, 0u, 0u, 0u);
        if (j < 197) {
            int tok = (j == 0) ? 0 : (1 + t * PP + (j - 1));
            vraw = *(const uint4*)(qkv + (bb + tok) * QKVN + 1536 + h * 64 + c);
        }
        f16x8 vv = *(f16x8*)&vraw;
#pragma unroll
        for (int e = 0; e < 8; e++) Vt[(c + e) * 232 + j] = vv[e];
    }
    __syncthreads();

    f16* myP = Ps + wave * 16 * 232;
    for (int qt = wave; qt < 13; qt += 4) {
        int mloc = qt * 16 + l15;
        int mc = mloc > 195 ? 195 : mloc;
        const f16* qr = qkv + (bb + 1 + (u64)t * PP + mc) * QKVN + h * 64;
        f16x8 qa0 = *(const f16x8*)(qr + quad * 8);
        f16x8 qa1 = *(const f16x8*)(qr + 32 + quad * 8);

        f32x4 s[13];
#pragma unroll
        for (int nt = 0; nt < 13; nt++) { s[nt][0] = 0.f; s[nt][1] = 0.f; s[nt][2] = 0.f; s[nt][3] = 0.f; }
#pragma unroll
        for (int nt = 0; nt < 13; nt++) {
            int n = nt * 16 + l15;
            int ncl = n > 196 ? 196 : n;
            int tok = (ncl == 0) ? 0 : (1 + t * PP + (ncl - 1));
            const f16* kr = qkv + (bb + tok) * QKVN + 768 + h * 64;
            f16x8 kb0 = *(const f16x8*)(kr + quad * 8);
            f16x8 kb1 = *(const f16x8*)(kr + 32 + quad * 8);
            s[nt] = __builtin_amdgcn_mfma_f32_16x16x32_f16(qa0, kb0, s[nt], 0, 0, 0);
            s[nt] = __builtin_amdgcn_mfma_f32_16x16x32_f16(qa1, kb1, s[nt], 0, 0, 0);
        }
        if (l15 >= 5) { s[12][0] = -1e30f; s[12][1] = -1e30f; s[12][2] = -1e30f; s[12][3] = -1e30f; }

        float mx[4] = {-1e30f, -1e30f, -1e30f, -1e30f};
#pragma unroll
        for (int nt = 0; nt < 13; nt++)
#pragma unroll
            for (int r = 0; r < 4; r++) mx[r] = fmaxf(mx[r], s[nt][r]);
#pragma unroll
        for (int m = 1; m < 16; m <<= 1)
#pragma unroll
            for (int r = 0; r < 4; r++) mx[r] = fmaxf(mx[r], __shfl_xor(mx[r], m, 64));

        float sum[4] = {0.f, 0.f, 0.f, 0.f};
#pragma unroll
        for (int nt = 0; nt < 13; nt++)
#pragma unroll
            for (int r = 0; r < 4; r++) {
                float p = exp2f((s[nt][r] - mx[r]) * 0.18033688011112042f);
                s[nt][r] = p;
                sum[r] += p;
            }
#pragma unroll
        for (int m = 1; m < 16; m <<= 1)
#pragma unroll
            for (int r = 0; r < 4; r++) sum[r] += __shfl_xor(sum[r], m, 64);

#pragma unroll
        for (int nt = 0; nt < 13; nt++)
#pragma unroll
            for (int r = 0; r < 4; r++)
                myP[(quad * 4 + r) * 232 + nt * 16 + l15] = (f16)s[nt][r];

        f32x4 o[4];
#pragma unroll
        for (int n2 = 0; n2 < 4; n2++) { o[n2][0] = 0.f; o[n2][1] = 0.f; o[n2][2] = 0.f; o[n2][3] = 0.f; }
#pragma unroll
        for (int kc = 0; kc < 7; kc++) {
            f16x8 pa = *(const f16x8*)(&myP[l15 * 232 + kc * 32 + quad * 8]);
#pragma unroll
            for (int n2 = 0; n2 < 4; n2++) {
                f16x8 vb = *(const f16x8*)(&Vt[(n2 * 16 + l15) * 232 + kc * 32 + quad * 8]);
                o[n2] = __builtin_amdgcn_mfma_f32_16x16x32_f16(pa, vb, o[n2], 0, 0, 0);
            }
        }

        float inv[4];
#pragma unroll
        for (int r = 0; r < 4; r++) inv[r] = 1.f / sum[r];
#pragma unroll
        for (int n2 = 0; n2 < 4; n2++)
#pragma unroll
            for (int r = 0; r < 4; r++) {
                int m = qt * 16 + quad * 4 + r;
                if (m < PP)
                    ctx[(bb + 1 + (u64)t * PP + m) * DM + h * 64 + n2 * 16 + l15] = (f16)(o[n2][r] * inv[r]);
            }
    }
}

// ---------------- host ----------------
extern "C" void kernel_launch(void* const* d_in, const int* in_sizes, int n_in,
                              void* d_out, int out_size, void* d_ws, size_t ws_size,
                              hipStream_t stream) {
    const float* x_in  = (const float*)d_in[0];
    const float* t_Wq  = (const float*)d_in[1];
    const float* t_bq  = (const float*)d_in[2];
    const float* t_Wk  = (const float*)d_in[3];
    const float* t_bk  = (const float*)d_in[4];
    const float* t_Wv  = (const float*)d_in[5];
    const float* t_bv  = (const float*)d_in[6];
    const float* t_Wo  = (const float*)d_in[7];
    const float* t_bo  = (const float*)d_in[8];
    const float* s_Wq  = (const float*)d_in[9];
    const float* s_bq  = (const float*)d_in[10];
    const float* s_Wk  = (const float*)d_in[11];
    const float* s_bk  = (const float*)d_in[12];
    const float* s_Wv  = (const float*)d_in[13];
    const float* s_bv  = (const float*)d_in[14];
    const float* s_Wo  = (const float*)d_in[15];
    const float* s_bo  = (const float*)d_in[16];
    const float* W1    = (const float*)d_in[17];
    const float* b1    = (const float*)d_in[18];
    const float* W2    = (const float*)d_in[19];
    const float* b2    = (const float*)d_in[20];
    const float* ln1g  = (const float*)d_in[21];
    const float* ln1b  = (const float*)d_in[22];
    const float* ln2g  = (const float*)d_in[23];
    const float* ln2b  = (const float*)d_in[24];
    const float* ln3g  = (const float*)d_in[25];
    const float* ln3b  = (const float*)d_in[26];

    char* ws = (char*)d_ws;
    f16* y    = (f16*)(ws + Y_OFF);
    f16* qkv  = (f16*)(ws + QKV_OFF);
    f16* ctx  = (f16*)(ws + CTX_OFF);
    f16* hbuf = (f16*)(ws + H_OFF);
    float* clsP = (float*)(ws + Y_OFF);   // reuses dead y region
    char* wreg = ws + W_OFF;
    f16* tQKV  = (f16*)(wreg);
    f16* tWoT  = (f16*)(wreg + 3538944);
    f16* sQKV  = (f16*)(wreg + 4718592);
    f16* sWoT  = (f16*)(wreg + 8257536);
    f16* W1T   = (f16*)(wreg + 9437184);
    f16* W2T   = (f16*)(wreg + 14155776);
    float* tBias = (float*)(wreg + 18874368);
    float* sBias = (float*)(wreg + 18883584);
    float* xcur  = (float*)d_out;

    dim3 tb(256);
    dim3 tb512(512);
    // --- weight prep ---
    transpose_kernel<<<dim3(24, 24), tb, 0, stream>>>(t_Wq, tQKV, 768, 768);
    transpose_kernel<<<dim3(24, 24), tb, 0, stream>>>(t_Wk, tQKV + 768 * 768, 768, 768);
    transpose_kernel<<<dim3(24, 24), tb, 0, stream>>>(t_Wv, tQKV + 2 * 768 * 768, 768, 768);
    transpose_kernel<<<dim3(24, 24), tb, 0, stream>>>(t_Wo, tWoT, 768, 768);
    transpose_kernel<<<dim3(24, 24), tb, 0, stream>>>(s_Wq, sQKV, 768, 768);
    transpose_kernel<<<dim3(24, 24), tb, 0, stream>>>(s_Wk, sQKV + 768 * 768, 768, 768);
    transpose_kernel<<<dim3(24, 24), tb, 0, stream>>>(s_Wv, sQKV + 2 * 768 * 768, 768, 768);
    transpose_kernel<<<dim3(24, 24), tb, 0, stream>>>(s_Wo, sWoT, 768, 768);
    transpose_kernel<<<dim3(96, 24), tb, 0, stream>>>(W1, W1T, 768, 3072);
    transpose_kernel<<<dim3(24, 96), tb, 0, stream>>>(W2, W2T, 3072, 768);
    bias3_kernel<<<3, tb, 0, stream>>>(t_bq, t_bk, t_bv, tBias);
    bias3_kernel<<<3, tb, 0, stream>>>(s_bq, s_bk, s_bv, sBias);

    // --- phase A: time MHA ---
    ln_kernel<<<3138, tb, 0, stream>>>(x_in, ln1g, ln1b, y);
    gemm256_kernel<QKVN, false><<<MB256 * 9, tb512, 0, stream>>>(y, tQKV, tBias, qkv, 768);
    time_attn_kernel<<<4704, tb, 0, stream>>>(qkv, ctx);
    cls_part_kernel<<<BQ * NH * CCH, tb, 0, stream>>>(qkv, clsP);
    cls_comb_kernel<<<24, tb, 0, stream>>>(clsP, ctx);
    gemm_kernel<DM, false, true, false><<<MB_PAD * 6, tb, 0, stream>>>(ctx, tWoT, t_bo, x_in, xcur, nullptr, 768);

    // --- phase B: space MHA ---
    ln_kernel<<<3138, tb, 0, stream>>>(xcur, ln2g, ln2b, y);
    gemm256_kernel<QKVN, false><<<MB256 * 9, tb512, 0, stream>>>(y, sQKV, sBias, qkv, 768);
    space_attn_kernel<<<768, tb, 0, stream>>>(qkv, ctx);
    cls_part_kernel<<<BQ * NH * CCH, tb, 0, stream>>>(qkv, clsP);
    cls_comb_kernel<<<24, tb, 0, stream>>>(clsP, ctx);
    gemm_kernel<DM, false, true, false><<<MB_PAD * 6, tb, 0, stream>>>(ctx, sWoT, s_bo, xcur, xcur, nullptr, 768);

    // --- phase C: MLP ---
    ln_kernel<<<3138, tb, 0, stream>>>(xcur, ln3g, ln3b, y);
    gemm256_kernel<D4, true><<<MB256 * 12, tb512, 0, stream>>>(y, W1T, b1, hbuf, 768);
    gemm_kernel<DM, false, true, false><<<MB_PAD * 6, tb, 0, stream>>>(hbuf, W2T, b2, xcur, xcur, nullptr, 3072);
}

// Round 2
// 895.192 us; speedup vs baseline: 1.0179x; 1.0179x over previous
//
#include <hip/hip_runtime.h>

// ---------------- problem constants ----------------
#define BQ   8
#define SQ   1569
#define BS   12552      // BQ*SQ
#define DM   768
#define NH   12
#define DH   64
#define TT   8
#define PP   196
#define D4   3072
#define QKVN 2304
#define CCH  24         // CLS split-K chunks
#define CKEY 66         // keys per chunk (24*66 = 1584 >= 1569)
#define MB_PAD 104      // 99 m-blocks padded to multiple of 8 for XCD-stable swizzle
#define MB256 50        // ceil(12552/256) real m-tiles for the 256 kernel
#define MBP256 56       // padded to multiple of 8: id%8 == mb%8 -> XCD-stable A slices

typedef _Float16 f16;
typedef _Float16 f16x8 __attribute__((ext_vector_type(8)));
typedef float    f32x4 __attribute__((ext_vector_type(4)));
typedef unsigned long long u64;

#define AS1 __attribute__((address_space(1)))
#define AS3 __attribute__((address_space(3)))

#define Y_OFF    0ULL
#define QKV_OFF  19279872ULL
#define CTX_OFF  77119488ULL
#define H_OFF    19279872ULL
#define W_OFF    96399360ULL

// ---------------- LayerNorm (wave per row) ----------------
__global__ __launch_bounds__(256) void ln_kernel(const float* __restrict__ x,
                                                 const float* __restrict__ g,
                                                 const float* __restrict__ bta,
                                                 f16* __restrict__ y) {
    int row = blockIdx.x * 4 + (threadIdx.x >> 6);
    int lane = threadIdx.x & 63;
    if (row >= BS) return;
    const float* xr = x + (u64)row * DM;
    float v[12];
    float s = 0.f, s2 = 0.f;
#pragma unroll
    for (int i = 0; i < 12; i++) { v[i] = xr[lane + i * 64]; s += v[i]; s2 += v[i] * v[i]; }
#pragma unroll
    for (int m = 1; m < 64; m <<= 1) { s += __shfl_xor(s, m, 64); s2 += __shfl_xor(s2, m, 64); }
    float mean = s * (1.f / 768.f);
    float var  = s2 * (1.f / 768.f) - mean * mean;
    float rstd = rsqrtf(var + 1e-12f);
    f16* yr = y + (u64)row * DM;
#pragma unroll
    for (int i = 0; i < 12; i++) {
        int c = lane + i * 64;
        yr[c] = (f16)((v[i] - mean) * rstd * g[c] + bta[c]);
    }
}

// ---------------- transpose fp32 -> f16 (dst[c*R+r] = src[r*C+c]) ----------------
__global__ __launch_bounds__(256) void transpose_kernel(const float* __restrict__ src,
                                                        f16* __restrict__ dst,
                                                        int R, int C) {
    __shared__ float tile[32][33];
    int bx = blockIdx.x * 32;
    int by = blockIdx.y * 32;
    int tx = threadIdx.x & 31, ty = threadIdx.x >> 5;
#pragma unroll
    for (int i = 0; i < 4; i++) {
        int r = by + ty + i * 8, c = bx + tx;
        if (r < R && c < C) tile[ty + i * 8][tx] = src[(u64)r * C + c];
    }
    __syncthreads();
#pragma unroll
    for (int i = 0; i < 4; i++) {
        int c = bx + ty + i * 8, r = by + tx;
        if (c < C && r < R) dst[(u64)c * R + r] = (f16)tile[tx][ty + i * 8];
    }
}

// ---------------- concat 3 bias vectors (768 each) ----------------
__global__ __launch_bounds__(256) void bias3_kernel(const float* __restrict__ a,
                                                    const float* __restrict__ b,
                                                    const float* __restrict__ c,
                                                    float* __restrict__ dst) {
    int i = blockIdx.x * 256 + threadIdx.x;
    if (i < 768) { dst[i] = a[i]; dst[i + 768] = b[i]; dst[i + 1536] = c[i]; }
}

// ---------------- GEMM v5 (kept for N=768 outputs): R4 staging + 1-barrier dbuf ----------------
template <int NOUT, bool GELU, bool RESID, bool OUTF16>
__global__ __launch_bounds__(256, 4) void gemm_kernel(const f16* __restrict__ A,
                                                      const f16* __restrict__ Bt,
                                                      const float* __restrict__ bias,
                                                      const float* __restrict__ resid,
                                                      float* __restrict__ Cf,
                                                      f16* __restrict__ Ch,
                                                      int K) {
    __shared__ __align__(16) f16 As[2][128 * 32];
    __shared__ __align__(16) f16 Bs[2][128 * 32];
    int id = blockIdx.x;
    int mb = id % MB_PAD, nb = id / MB_PAD;
    if (mb >= 99) return;
    int tid  = threadIdx.x;
    int lane = tid & 63, wave = tid >> 6;
    int wm = wave >> 1, wn = wave & 1;
    int m0 = mb * 128, n0 = nb * 128;
    int l15 = lane & 15, quad = lane >> 4;

    int r0   = wave * 16 + (lane >> 2);
    int coff = (lane & 3) * 8;
    const f16* ag0 = A + (u64)(m0 + r0) * K + coff;
    const f16* ag1 = A + (u64)(m0 + r0 + 64) * K + coff;
    bool av0 = (m0 + r0) < BS, av1 = (m0 + r0 + 64) < BS;
    const f16* bg0 = Bt + (u64)(n0 + r0) * K + coff;
    const f16* bg1 = Bt + (u64)(n0 + r0 + 64) * K + coff;
    int lofs = wave * 1024;

    f32x4 acc[4][4];
#pragma unroll
    for (int i = 0; i < 4; i++)
#pragma unroll
        for (int j = 0; j < 4; j++)
#pragma unroll
            for (int r = 0; r < 4; r++) acc[i][j][r] = 0.f;

    if (av0) __builtin_amdgcn_global_load_lds((const AS1 void*)ag0, (AS3 void*)((AS3 char*)&As[0][0] + lofs), 16, 0, 0);
    if (av1) __builtin_amdgcn_global_load_lds((const AS1 void*)ag1, (AS3 void*)((AS3 char*)&As[0][0] + lofs + 4096), 16, 0, 0);
    __builtin_amdgcn_global_load_lds((const AS1 void*)bg0, (AS3 void*)((AS3 char*)&Bs[0][0] + lofs), 16, 0, 0);
    __builtin_amdgcn_global_load_lds((const AS1 void*)bg1, (AS3 void*)((AS3 char*)&Bs[0][0] + lofs + 4096), 16, 0, 0);
    ag0 += 32; ag1 += 32; bg0 += 32; bg1 += 32;

    int nit = K >> 5;
    for (int it = 0; it < nit; it++) {
        __syncthreads();
        int buf = it & 1;
        if (it + 1 < nit) {
            int nb2 = buf ^ 1;
            if (av0) __builtin_amdgcn_global_load_lds((const AS1 void*)ag0, (AS3 void*)((AS3 char*)&As[nb2][0] + lofs), 16, 0, 0);
            if (av1) __builtin_amdgcn_global_load_lds((const AS1 void*)ag1, (AS3 void*)((AS3 char*)&As[nb2][0] + lofs + 4096), 16, 0, 0);
            __builtin_amdgcn_global_load_lds((const AS1 void*)bg0, (AS3 void*)((AS3 char*)&Bs[nb2][0] + lofs), 16, 0, 0);
            __builtin_amdgcn_global_load_lds((const AS1 void*)bg1, (AS3 void*)((AS3 char*)&Bs[nb2][0] + lofs + 4096), 16, 0, 0);
            ag0 += 32; ag1 += 32; bg0 += 32; bg1 += 32;
        }
        f16x8 af[4], bf[4];
#pragma unroll
        for (int i = 0; i < 4; i++)
            af[i] = *(const f16x8*)(&As[buf][(wm * 64 + i * 16 + l15) * 32 + quad * 8]);
#pragma unroll
        for (int j = 0; j < 4; j++)
            bf[j] = *(const f16x8*)(&Bs[buf][(wn * 64 + j * 16 + l15) * 32 + quad * 8]);
#pragma unroll
        for (int i = 0; i < 4; i++)
#pragma unroll
            for (int j = 0; j < 4; j++)
                acc[i][j] = __builtin_amdgcn_mfma_f32_16x16x32_f16(af[i], bf[j], acc[i][j], 0, 0, 0);
    }

#pragma unroll
    for (int i = 0; i < 4; i++) {
#pragma unroll
        for (int j = 0; j < 4; j++) {
            int col = n0 + wn * 64 + j * 16 + l15;
            float bv = bias[col];
#pragma unroll
            for (int r = 0; r < 4; r++) {
                int row = m0 + wm * 64 + i * 16 + quad * 4 + r;
                if (row < BS) {
                    float v = acc[i][j][r] + bv;
                    if (GELU) {
                        float u = 0.7978845608028654f * (v + 0.044715f * v * v * v);
                        float e = __builtin_exp2f(-2.885390081777927f * u);
                        v = v / (1.f + e);
                    }
                    if (RESID) v += resid[(u64)row * NOUT + col];
                    if (OUTF16) Ch[(u64)row * NOUT + col] = (f16)v;
                    else        Cf[(u64)row * NOUT + col] = v;
                }
            }
        }
    }
}

// ---------------- GEMM v6.1: 256x256 8-phase pipeline, XCD-stable + tile-chained ----------------
// Changes vs v6 (which regressed: FETCH 2.2x from L2 thrash, 3-round makespan, over-strict
// lgkmcnt(0)):
//  - mb padded to MBP256=56 (mult of 8): tile%8 == mb%8 -> each XCD L2 holds a fixed A slice.
//  - tile-chain loop with grid stride (stride % 8 == 0 keeps XCD stability); FFN1 launches
//    grid 512 so 600 real tiles finish in 2 rounds instead of 3.
//  - dropped explicit lgkmcnt(0): compiler emits fine-grained lgkmcnt(N) per MFMA dataflow,
//    so early MFMAs start while later ds_reads are in flight.
// Sync schedule otherwise unchanged: counted vmcnt(4) once per K-tile at P4 (drain 0 at
// tail), 2 raw s_barrier per phase, setprio(1) around MFMA clusters.
template <int NOUT, bool GELU>
__global__ __launch_bounds__(512, 2) void gemm256_kernel(const f16* __restrict__ A,
                                                         const f16* __restrict__ Bt,
                                                         const float* __restrict__ bias,
                                                         f16* __restrict__ Ch,
                                                         int K, int ntiles) {
    __shared__ __align__(16) f16 lds[2][2][16384];
    int tid = threadIdx.x;
    int lane = tid & 63, wave = tid >> 6;
    int pm = wave >> 2, pn = wave & 3;
    int l15 = lane & 15, quad = lane >> 4;
    int s7 = l15 & 7;
    int g0 = (quad ^ s7) << 4;           // byte offset of swizzled granule, kk=0
    int g1 = ((quad ^ s7) ^ 4) << 4;     // kk=1
    int rbA = (pm * 64 + l15) * 128;     // byte row base within A tile (qm=0)
    int rbB = (pn * 32 + l15) * 128;
    int srow8 = (wave << 3) + (lane >> 3);
    u64 sgel = (u64)(((lane & 7) ^ (lane >> 3)) << 3);

  for (int tix = blockIdx.x; tix < ntiles; tix += gridDim.x) {
    int mb = tix % MBP256, nb = tix / MBP256;
    if (mb >= MB256) continue;
    int m0 = mb * 256, n0 = nb * 256;

    u64 offA[4], offB[4];                // element offsets per (half,q)
#pragma unroll
    for (int i = 0; i < 4; i++) {
        int ra = m0 + i * 64 + srow8; if (ra > BS - 1) ra = BS - 1;   // clamp M tail
        offA[i] = (u64)ra * K + sgel;
        offB[i] = (u64)(n0 + i * 64 + srow8) * K + sgel;
    }

#define STAGE_A(BUF, HALF, KT) { \
    AS3 char* _d = (AS3 char*)&lds[BUF][0][0] + (HALF) * 16384 + wave * 1024; \
    __builtin_amdgcn_global_load_lds((const AS1 void*)(A + offA[(HALF) * 2]     + (u64)(KT) * 64), (AS3 void*)_d, 16, 0, 0); \
    __builtin_amdgcn_global_load_lds((const AS1 void*)(A + offA[(HALF) * 2 + 1] + (u64)(KT) * 64), (AS3 void*)(_d + 8192), 16, 0, 0); \
}
#define STAGE_B(BUF, HALF, KT) { \
    AS3 char* _d = (AS3 char*)&lds[BUF][1][0] + (HALF) * 16384 + wave * 1024; \
    __builtin_amdgcn_global_load_lds((const AS1 void*)(Bt + offB[(HALF) * 2]     + (u64)(KT) * 64), (AS3 void*)_d, 16, 0, 0); \
    __builtin_amdgcn_global_load_lds((const AS1 void*)(Bt + offB[(HALF) * 2 + 1] + (u64)(KT) * 64), (AS3 void*)(_d + 8192), 16, 0, 0); \
}
#define PH_READ_A(QM) { \
    _Pragma("unroll") for (int im = 0; im < 4; im++) { \
        af[im][0] = *(const f16x8*)(Ap + (QM) * 16384 + rbA + im * 2048 + g0); \
        af[im][1] = *(const f16x8*)(Ap + (QM) * 16384 + rbA + im * 2048 + g1); \
    } }
#define PH_READ_B(QN) { \
    _Pragma("unroll") for (int jn = 0; jn < 2; jn++) { \
        bf[jn][0] = *(const f16x8*)(Bp + (QN) * 16384 + rbB + jn * 2048 + g0); \
        bf[jn][1] = *(const f16x8*)(Bp + (QN) * 16384 + rbB + jn * 2048 + g1); \
    } }
#define PH_MMA(QM, QN) { \
    __builtin_amdgcn_s_setprio(1); \
    _Pragma("unroll") for (int im = 0; im < 4; im++) \
    _Pragma("unroll") for (int jn = 0; jn < 2; jn++) { \
        acc[QM][QN][im][jn] = __builtin_amdgcn_mfma_f32_16x16x32_f16(af[im][0], bf[jn][0], acc[QM][QN][im][jn], 0, 0, 0); \
        acc[QM][QN][im][jn] = __builtin_amdgcn_mfma_f32_16x16x32_f16(af[im][1], bf[jn][1], acc[QM][QN][im][jn], 0, 0, 0); \
    } \
    __builtin_amdgcn_s_setprio(0); \
}

    f32x4 acc[2][2][4][2];
#pragma unroll
    for (int a = 0; a < 2; a++)
#pragma unroll
        for (int b = 0; b < 2; b++)
#pragma unroll
            for (int c = 0; c < 4; c++)
#pragma unroll
                for (int d = 0; d < 2; d++)
#pragma unroll
                    for (int r = 0; r < 4; r++) acc[a][b][c][d][r] = 0.f;
    f16x8 af[4][2], bf[2][2];

    int nk = K >> 6;   // K-tiles of 64 (requires nk >= 2; K=768 -> 12)
    // prologue: tile 0 complete + tile 1's A0,B1 (the "(k-1).P3/P4" slots for k=0)
    STAGE_A(0, 0, 0); STAGE_B(0, 0, 0); STAGE_A(0, 1, 0); STAGE_B(0, 1, 0);
    STAGE_A(1, 0, 1); STAGE_B(1, 1, 1);
    asm volatile("s_waitcnt vmcnt(4)");   // tile 0's 8 loads landed, 4 in flight
    __builtin_amdgcn_s_barrier();

    for (int kt = 0; kt < nk; kt++) {
        int buf = kt & 1, bufn = buf ^ 1;
        const char* Ap = (const char*)&lds[buf][0][0];
        const char* Bp = (const char*)&lds[buf][1][0];
        bool s1 = (kt + 1 < nk), s2 = (kt + 2 < nk);
        // P1: quadrant (0,0); stage A1(kt+1)
        PH_READ_A(0); PH_READ_B(0);
        if (s1) STAGE_A(bufn, 1, kt + 1);
        __builtin_amdgcn_s_barrier();
        PH_MMA(0, 0);
        __builtin_amdgcn_s_barrier();
        // P2: quadrant (0,1); stage B0(kt+1)
        PH_READ_B(1);
        if (s1) STAGE_B(bufn, 0, kt + 1);
        __builtin_amdgcn_s_barrier();
        PH_MMA(0, 1);
        __builtin_amdgcn_s_barrier();
        // P3: quadrant (1,1); stage A0(kt+2)
        PH_READ_A(1);
        if (s2) STAGE_A(buf, 0, kt + 2);
        __builtin_amdgcn_s_barrier();
        PH_MMA(1, 1);
        __builtin_amdgcn_s_barrier();
        // P4: quadrant (1,0); stage B1(kt+2); counted vmcnt keeps 4 loads in flight
        PH_READ_B(0);
        if (s2) STAGE_B(buf, 1, kt + 2);
        if (s2) { asm volatile("s_waitcnt vmcnt(4)"); }
        else    { asm volatile("s_waitcnt vmcnt(0)"); }
        __builtin_amdgcn_s_barrier();
        PH_MMA(1, 0);
        __builtin_amdgcn_s_barrier();
    }

    // epilogue
    int quad4 = quad << 2;
#pragma unroll
    for (int qn = 0; qn < 2; qn++)
#pragma unroll
        for (int jn = 0; jn < 2; jn++) {
            int col = n0 + qn * 128 + pn * 32 + jn * 16 + l15;
            float bv = bias[col];
#pragma unroll
            for (int qm = 0; qm < 2; qm++)
#pragma unroll
                for (int im = 0; im < 4; im++) {
                    int rowb = m0 + qm * 128 + pm * 64 + im * 16 + quad4;
#pragma unroll
                    for (int r = 0; r < 4; r++) {
                        int row = rowb + r;
                        if (row < BS) {
                            float v = acc[qm][qn][im][jn][r] + bv;
                            if (GELU) {
                                float u = 0.7978845608028654f * (v + 0.044715f * v * v * v);
                                float e = __builtin_exp2f(-2.885390081777927f * u);
                                v = v / (1.f + e);
                            }
                            Ch[(u64)row * NOUT + col] = (f16)v;
                        }
                    }
                }
        }
#undef STAGE_A
#undef STAGE_B
#undef PH_READ_A
#undef PH_READ_B
#undef PH_MMA
  }
}

// ---------------- time attention: wave per (b,h,p); 8 queries x 9 keys ----------------
__global__ __launch_bounds__(256) void time_attn_kernel(const f16* __restrict__ qkv,
                                                        f16* __restrict__ ctx) {
    int w = blockIdx.x * 4 + (threadIdx.x >> 6);
    int lane = threadIdx.x & 63;
    int b = w / (NH * PP);
    int rem = w % (NH * PP);
    int h = rem / PP, p = rem % PP;
    u64 bb = (u64)b * SQ;
    int hoff = h * 64 + lane;

    float qv[TT], kv[9], vv[9];
#pragma unroll
    for (int t = 0; t < TT; t++) qv[t] = (float)qkv[(bb + 1 + t * PP + p) * QKVN + hoff];
    kv[0] = (float)qkv[bb * QKVN + 768 + hoff];
    vv[0] = (float)qkv[bb * QKVN + 1536 + hoff];
#pragma unroll
    for (int j = 1; j <= TT; j++) {
        u64 ro = (bb + 1 + (u64)(j - 1) * PP + p) * QKVN;
        kv[j] = (float)qkv[ro + 768 + hoff];
        vv[j] = (float)qkv[ro + 1536 + hoff];
    }
#pragma unroll
    for (int t = 0; t < TT; t++) {
        float s[9];
#pragma unroll
        for (int j = 0; j < 9; j++) {
            float ps = qv[t] * kv[j];
#pragma unroll
            for (int m = 1; m < 64; m <<= 1) ps += __shfl_xor(ps, m, 64);
            s[j] = ps * 0.125f;
        }
        float mx = s[0];
#pragma unroll
        for (int j = 1; j < 9; j++) mx = fmaxf(mx, s[j]);
        float sum = 0.f;
#pragma unroll
        for (int j = 0; j < 9; j++) { s[j] = expf(s[j] - mx); sum += s[j]; }
        float o = 0.f;
#pragma unroll
        for (int j = 0; j < 9; j++) o += s[j] * vv[j];
        o /= sum;
        ctx[(bb + 1 + (u64)t * PP + p) * DM + h * 64 + lane] = (f16)o;
    }
}

// ---------------- CLS attention split-K: part kernel, block per (b,h,chunk) ----------------
__global__ __launch_bounds__(256) void cls_part_kernel(const f16* __restrict__ qkv,
                                                       float* __restrict__ part) {
    int g = blockIdx.x;
    int c = g % CCH, bh = g / CCH;
    int b = bh / NH, h = bh % NH;
    u64 bb = (u64)b * SQ;
    int tid = threadIdx.x, lane = tid & 63, wave = tid >> 6;
    __shared__ float sc[CKEY];
    __shared__ float accbuf[4][64];
    __shared__ float lbuf[4];
    __shared__ float mxs;
    float qd = (float)qkv[bb * QKVN + h * 64 + lane];
    int j0 = c * CKEY;
    int cnt = SQ - j0; if (cnt > CKEY) cnt = CKEY;
    for (int jj = wave; jj < cnt; jj += 4) {
        float p = qd * (float)qkv[(bb + j0 + jj) * QKVN + 768 + h * 64 + lane];
#pragma unroll
        for (int m = 1; m < 64; m <<= 1) p += __shfl_xor(p, m, 64);
        if (lane == 0) sc[jj] = p * 0.125f;
    }
    __syncthreads();
    if (wave == 0) {
        float m = -1e30f;
        for (int j = lane; j < cnt; j += 64) m = fmaxf(m, sc[j]);
#pragma unroll
        for (int s = 1; s < 64; s <<= 1) m = fmaxf(m, __shfl_xor(m, s, 64));
        if (lane == 0) mxs = m;
    }
    __syncthreads();
    float mx = mxs;
    float acc = 0.f, l = 0.f;
    for (int jj = wave; jj < cnt; jj += 4) {
        float w = expf(sc[jj] - mx);
        l += w;
        acc += w * (float)qkv[(bb + j0 + jj) * QKVN + 1536 + h * 64 + lane];
    }
    accbuf[wave][lane] = acc;
    if (lane == 0) lbuf[wave] = l;
    __syncthreads();
    if (tid < 64) {
        float a = accbuf[0][tid] + accbuf[1][tid] + accbuf[2][tid] + accbuf[3][tid];
        float* pb = part + ((u64)bh * CCH + c) * 66;
        if (tid == 0) { pb[0] = mxs; pb[1] = lbuf[0] + lbuf[1] + lbuf[2] + lbuf[3]; }
        pb[2 + tid] = a;
    }
}

// ---------------- CLS attention split-K: combine kernel, wave per (b,h) ----------------
__global__ __launch_bounds__(256) void cls_comb_kernel(const float* __restrict__ part,
                                                       f16* __restrict__ ctx) {
    int w = blockIdx.x * 4 + (threadIdx.x >> 6);
    int lane = threadIdx.x & 63;
    if (w >= BQ * NH) return;
    int b = w / NH, h = w % NH;
    const float* pb = part + (u64)w * CCH * 66;
    float m = (lane < CCH) ? pb[lane * 66] : -1e30f;
#pragma unroll
    for (int s = 1; s < 64; s <<= 1) m = fmaxf(m, __shfl_xor(m, s, 64));
    float l = (lane < CCH) ? pb[lane * 66 + 1] * expf(pb[lane * 66] - m) : 0.f;
#pragma unroll
    for (int s = 1; s < 64; s <<= 1) l += __shfl_xor(l, s, 64);
    float o = 0.f;
    for (int j = 0; j < CCH; j++) {
        float mj = pb[j * 66];
        o += pb[j * 66 + 2 + lane] * expf(mj - m);
    }
    ctx[((u64)b * SQ) * DM + h * 64 + lane] = (f16)(o / l);
}

// ---------------- space attention: MFMA flash, block per (b,h,t) ----------------
__global__ __launch_bounds__(256) void space_attn_kernel(const f16* __restrict__ qkv,
                                                         f16* __restrict__ ctx) {
    int g = blockIdx.x;
    int b = g / (NH * TT);
    int rem = g % (NH * TT);
    int h = rem / TT, t = rem % TT;
    __shared__ __align__(16) f16 Vt[64 * 232];
    __shared__ __align__(16) f16 Ps[4 * 16 * 232];
    u64 bb = (u64)b * SQ;
    int tid = threadIdx.x, lane = tid & 63, wave = tid >> 6;
    int l15 = lane & 15, quad = lane >> 4;

    for (int i = tid; i < 4 * 16 * 232 * 2 / 16; i += 256)
        ((uint4*)Ps)[i] = make_uint4(0u, 0u, 0u, 0u);

    for (int idx = tid; idx < 232 * 8; idx += 256) {
        int c8 = idx / 232;
        int j  = idx - c8 * 232;
        int c  = c8 * 8;
        uint4 vraw = make_uint4(0u, 0u, 0u, 0u);
        if (j < 197) {
            int tok = (j == 0) ? 0 : (1 + t * PP + (j - 1));
            vraw = *(const uint4*)(qkv + (bb + tok) * QKVN + 1536 + h * 64 + c);
        }
        f16x8 vv = *(f16x8*)&vraw;
#pragma unroll
        for (int e = 0; e < 8; e++) Vt[(c + e) * 232 + j] = vv[e];
    }
    __syncthreads();

    f16* myP = Ps + wave * 16 * 232;
    for (int qt = wave; qt < 13; qt += 4) {
        int mloc = qt * 16 + l15;
        int mc = mloc > 195 ? 195 : mloc;
        const f16* qr = qkv + (bb + 1 + (u64)t * PP + mc) * QKVN + h * 64;
        f16x8 qa0 = *(const f16x8*)(qr + quad * 8);
        f16x8 qa1 = *(const f16x8*)(qr + 32 + quad * 8);

        f32x4 s[13];
#pragma unroll
        for (int nt = 0; nt < 13; nt++) { s[nt][0] = 0.f; s[nt][1] = 0.f; s[nt][2] = 0.f; s[nt][3] = 0.f; }
#pragma unroll
        for (int nt = 0; nt < 13; nt++) {
            int n = nt * 16 + l15;
            int ncl = n > 196 ? 196 : n;
            int tok = (ncl == 0) ? 0 : (1 + t * PP + (ncl - 1));
            const f16* kr = qkv + (bb + tok) * QKVN + 768 + h * 64;
            f16x8 kb0 = *(const f16x8*)(kr + quad * 8);
            f16x8 kb1 = *(const f16x8*)(kr + 32 + quad * 8);
            s[nt] = __builtin_amdgcn_mfma_f32_16x16x32_f16(qa0, kb0, s[nt], 0, 0, 0);
            s[nt] = __builtin_amdgcn_mfma_f32_16x16x32_f16(qa1, kb1, s[nt], 0, 0, 0);
        }
        if (l15 >= 5) { s[12][0] = -1e30f; s[12][1] = -1e30f; s[12][2] = -1e30f; s[12][3] = -1e30f; }

        float mx[4] = {-1e30f, -1e30f, -1e30f, -1e30f};
#pragma unroll
        for (int nt = 0; nt < 13; nt++)
#pragma unroll
            for (int r = 0; r < 4; r++) mx[r] = fmaxf(mx[r], s[nt][r]);
#pragma unroll
        for (int m = 1; m < 16; m <<= 1)
#pragma unroll
            for (int r = 0; r < 4; r++) mx[r] = fmaxf(mx[r], __shfl_xor(mx[r], m, 64));

        float sum[4] = {0.f, 0.f, 0.f, 0.f};
#pragma unroll
        for (int nt = 0; nt < 13; nt++)
#pragma unroll
            for (int r = 0; r < 4; r++) {
                float p = exp2f((s[nt][r] - mx[r]) * 0.18033688011112042f);
                s[nt][r] = p;
                sum[r] += p;
            }
#pragma unroll
        for (int m = 1; m < 16; m <<= 1)
#pragma unroll
            for (int r = 0; r < 4; r++) sum[r] += __shfl_xor(sum[r], m, 64);

#pragma unroll
        for (int nt = 0; nt < 13; nt++)
#pragma unroll
            for (int r = 0; r < 4; r++)
                myP[(quad * 4 + r) * 232 + nt * 16 + l15] = (f16)s[nt][r];

        f32x4 o[4];
#pragma unroll
        for (int n2 = 0; n2 < 4; n2++) { o[n2][0] = 0.f; o[n2][1] = 0.f; o[n2][2] = 0.f; o[n2][3] = 0.f; }
#pragma unroll
        for (int kc = 0; kc < 7; kc++) {
            f16x8 pa = *(const f16x8*)(&myP[l15 * 232 + kc * 32 + quad * 8]);
#pragma unroll
            for (int n2 = 0; n2 < 4; n2++) {
                f16x8 vb = *(const f16x8*)(&Vt[(n2 * 16 + l15) * 232 + kc * 32 + quad * 8]);
                o[n2] = __builtin_amdgcn_mfma_f32_16x16x32_f16(pa, vb, o[n2], 0, 0, 0);
            }
        }

        float inv[4];
#pragma unroll
        for (int r = 0; r < 4; r++) inv[r] = 1.f / sum[r];
#pragma unroll
        for (int n2 = 0; n2 < 4; n2++)
#pragma unroll
            for (int r = 0; r < 4; r++) {
                int m = qt * 16 + quad * 4 + r;
                if (m < PP)
                    ctx[(bb + 1 + (u64)t * PP + m) * DM + h * 64 + n2 * 16 + l15] = (f16)(o[n2][r] * inv[r]);
            }
    }
}

// ---------------- host ----------------
extern "C" void kernel_launch(void* const* d_in, const int* in_sizes, int n_in,
                              void* d_out, int out_size, void* d_ws, size_t ws_size,
                              hipStream_t stream) {
    const float* x_in  = (const float*)d_in[0];
    const float* t_Wq  = (const float*)d_in[1];
    const float* t_bq  = (const float*)d_in[2];
    const float* t_Wk  = (const float*)d_in[3];
    const float* t_bk  = (const float*)d_in[4];
    const float* t_Wv  = (const float*)d_in[5];
    const float* t_bv  = (const float*)d_in[6];
    const float* t_Wo  = (const float*)d_in[7];
    const float* t_bo  = (const float*)d_in[8];
    const float* s_Wq  = (const float*)d_in[9];
    const float* s_bq  = (const float*)d_in[10];
    const float* s_Wk  = (const float*)d_in[11];
    const float* s_bk  = (const float*)d_in[12];
    const float* s_Wv  = (const float*)d_in[13];
    const float* s_bv  = (const float*)d_in[14];
    const float* s_Wo  = (const float*)d_in[15];
    const float* s_bo  = (const float*)d_in[16];
    const float* W1    = (const float*)d_in[17];
    const float* b1    = (const float*)d_in[18];
    const float* W2    = (const float*)d_in[19];
    const float* b2    = (const float*)d_in[20];
    const float* ln1g  = (const float*)d_in[21];
    const float* ln1b  = (const float*)d_in[22];
    const float* ln2g  = (const float*)d_in[23];
    const float* ln2b  = (const float*)d_in[24];
    const float* ln3g  = (const float*)d_in[25];
    const float* ln3b  = (const float*)d_in[26];

    char* ws = (char*)d_ws;
    f16* y    = (f16*)(ws + Y_OFF);
    f16* qkv  = (f16*)(ws + QKV_OFF);
    f16* ctx  = (f16*)(ws + CTX_OFF);
    f16* hbuf = (f16*)(ws + H_OFF);
    float* clsP = (float*)(ws + Y_OFF);   // reuses dead y region
    char* wreg = ws + W_OFF;
    f16* tQKV  = (f16*)(wreg);
    f16* tWoT  = (f16*)(wreg + 3538944);
    f16* sQKV  = (f16*)(wreg + 4718592);
    f16* sWoT  = (f16*)(wreg + 8257536);
    f16* W1T   = (f16*)(wreg + 9437184);
    f16* W2T   = (f16*)(wreg + 14155776);
    float* tBias = (float*)(wreg + 18874368);
    float* sBias = (float*)(wreg + 18883584);
    float* xcur  = (float*)d_out;

    dim3 tb(256);
    dim3 tb512(512);
    // --- weight prep ---
    transpose_kernel<<<dim3(24, 24), tb, 0, stream>>>(t_Wq, tQKV, 768, 768);
    transpose_kernel<<<dim3(24, 24), tb, 0, stream>>>(t_Wk, tQKV + 768 * 768, 768, 768);
    transpose_kernel<<<dim3(24, 24), tb, 0, stream>>>(t_Wv, tQKV + 2 * 768 * 768, 768, 768);
    transpose_kernel<<<dim3(24, 24), tb, 0, stream>>>(t_Wo, tWoT, 768, 768);
    transpose_kernel<<<dim3(24, 24), tb, 0, stream>>>(s_Wq, sQKV, 768, 768);
    transpose_kernel<<<dim3(24, 24), tb, 0, stream>>>(s_Wk, sQKV + 768 * 768, 768, 768);
    transpose_kernel<<<dim3(24, 24), tb, 0, stream>>>(s_Wv, sQKV + 2 * 768 * 768, 768, 768);
    transpose_kernel<<<dim3(24, 24), tb, 0, stream>>>(s_Wo, sWoT, 768, 768);
    transpose_kernel<<<dim3(96, 24), tb, 0, stream>>>(W1, W1T, 768, 3072);
    transpose_kernel<<<dim3(24, 96), tb, 0, stream>>>(W2, W2T, 3072, 768);
    bias3_kernel<<<3, tb, 0, stream>>>(t_bq, t_bk, t_bv, tBias);
    bias3_kernel<<<3, tb, 0, stream>>>(s_bq, s_bk, s_bv, sBias);

    // --- phase A: time MHA ---
    ln_kernel<<<3138, tb, 0, stream>>>(x_in, ln1g, ln1b, y);
    gemm256_kernel<QKVN, false><<<504, tb512, 0, stream>>>(y, tQKV, tBias, qkv, 768, MBP256 * 9);
    time_attn_kernel<<<4704, tb, 0, stream>>>(qkv, ctx);
    cls_part_kernel<<<BQ * NH * CCH, tb, 0, stream>>>(qkv, clsP);
    cls_comb_kernel<<<24, tb, 0, stream>>>(clsP, ctx);
    gemm_kernel<DM, false, true, false><<<MB_PAD * 6, tb, 0, stream>>>(ctx, tWoT, t_bo, x_in, xcur, nullptr, 768);

    // --- phase B: space MHA ---
    ln_kernel<<<3138, tb, 0, stream>>>(xcur, ln2g, ln2b, y);
    gemm256_kernel<QKVN, false><<<504, tb512, 0, stream>>>(y, sQKV, sBias, qkv, 768, MBP256 * 9);
    space_attn_kernel<<<768, tb, 0, stream>>>(qkv, ctx);
    cls_part_kernel<<<BQ * NH * CCH, tb, 0, stream>>>(qkv, clsP);
    cls_comb_kernel<<<24, tb, 0, stream>>>(clsP, ctx);
    gemm_kernel<DM, false, true, false><<<MB_PAD * 6, tb, 0, stream>>>(ctx, sWoT, s_bo, xcur, xcur, nullptr, 768);

    // --- phase C: MLP ---
    ln_kernel<<<3138, tb, 0, stream>>>(xcur, ln3g, ln3b, y);
    gemm256_kernel<D4, true><<<512, tb512, 0, stream>>>(y, W1T, b1, hbuf, 768, MBP256 * 12);
    gemm_kernel<DM, false, true, false><<<MB_PAD * 6, tb, 0, stream>>>(hbuf, W2T, b2, xcur, xcur, nullptr, 3072);
}

// Round 3
// 893.971 us; speedup vs baseline: 1.0193x; 1.0014x over previous
//
#include <hip/hip_runtime.h>

// ---------------- problem constants ----------------
#define BQ   8
#define SQ   1569
#define BS   12552      // BQ*SQ
#define DM   768
#define NH   12
#define DH   64
#define TT   8
#define PP   196
#define D4   3072
#define QKVN 2304
#define CCH  24         // CLS split-K chunks
#define CKEY 66         // keys per chunk (24*66 = 1584 >= 1569)
#define MB_PAD 104      // 99 m-blocks padded to multiple of 8 for XCD-stable swizzle
#define MB256 50        // ceil(12552/256) real m-tiles for the 256 kernel
#define MBP256 56       // padded to multiple of 8: tix%8 == mb%8 -> XCD-stable A slices

typedef _Float16 f16;
typedef _Float16 f16x8 __attribute__((ext_vector_type(8)));
typedef float    f32x4 __attribute__((ext_vector_type(4)));
typedef unsigned long long u64;

#define AS1 __attribute__((address_space(1)))
#define AS3 __attribute__((address_space(3)))

#define Y_OFF    0ULL
#define QKV_OFF  19279872ULL
#define CTX_OFF  77119488ULL
#define H_OFF    19279872ULL
#define W_OFF    96399360ULL

// ---------------- LayerNorm (wave per row) ----------------
__global__ __launch_bounds__(256) void ln_kernel(const float* __restrict__ x,
                                                 const float* __restrict__ g,
                                                 const float* __restrict__ bta,
                                                 f16* __restrict__ y) {
    int row = blockIdx.x * 4 + (threadIdx.x >> 6);
    int lane = threadIdx.x & 63;
    if (row >= BS) return;
    const float* xr = x + (u64)row * DM;
    float v[12];
    float s = 0.f, s2 = 0.f;
#pragma unroll
    for (int i = 0; i < 12; i++) { v[i] = xr[lane + i * 64]; s += v[i]; s2 += v[i] * v[i]; }
#pragma unroll
    for (int m = 1; m < 64; m <<= 1) { s += __shfl_xor(s, m, 64); s2 += __shfl_xor(s2, m, 64); }
    float mean = s * (1.f / 768.f);
    float var  = s2 * (1.f / 768.f) - mean * mean;
    float rstd = rsqrtf(var + 1e-12f);
    f16* yr = y + (u64)row * DM;
#pragma unroll
    for (int i = 0; i < 12; i++) {
        int c = lane + i * 64;
        yr[c] = (f16)((v[i] - mean) * rstd * g[c] + bta[c]);
    }
}

// ---------------- transpose fp32 -> f16 (dst[c*R+r] = src[r*C+c]) ----------------
__global__ __launch_bounds__(256) void transpose_kernel(const float* __restrict__ src,
                                                        f16* __restrict__ dst,
                                                        int R, int C) {
    __shared__ float tile[32][33];
    int bx = blockIdx.x * 32;
    int by = blockIdx.y * 32;
    int tx = threadIdx.x & 31, ty = threadIdx.x >> 5;
#pragma unroll
    for (int i = 0; i < 4; i++) {
        int r = by + ty + i * 8, c = bx + tx;
        if (r < R && c < C) tile[ty + i * 8][tx] = src[(u64)r * C + c];
    }
    __syncthreads();
#pragma unroll
    for (int i = 0; i < 4; i++) {
        int c = bx + ty + i * 8, r = by + tx;
        if (c < C && r < R) dst[(u64)c * R + r] = (f16)tile[tx][ty + i * 8];
    }
}

// ---------------- concat 3 bias vectors (768 each) ----------------
__global__ __launch_bounds__(256) void bias3_kernel(const float* __restrict__ a,
                                                    const float* __restrict__ b,
                                                    const float* __restrict__ c,
                                                    float* __restrict__ dst) {
    int i = blockIdx.x * 256 + threadIdx.x;
    if (i < 768) { dst[i] = a[i]; dst[i + 768] = b[i]; dst[i + 1536] = c[i]; }
}

// ---------------- GEMM v5 (kept for N=768 outputs): R4 staging + 1-barrier dbuf ----------------
template <int NOUT, bool GELU, bool RESID, bool OUTF16>
__global__ __launch_bounds__(256, 4) void gemm_kernel(const f16* __restrict__ A,
                                                      const f16* __restrict__ Bt,
                                                      const float* __restrict__ bias,
                                                      const float* __restrict__ resid,
                                                      float* __restrict__ Cf,
                                                      f16* __restrict__ Ch,
                                                      int K) {
    __shared__ __align__(16) f16 As[2][128 * 32];
    __shared__ __align__(16) f16 Bs[2][128 * 32];
    int id = blockIdx.x;
    int mb = id % MB_PAD, nb = id / MB_PAD;
    if (mb >= 99) return;
    int tid  = threadIdx.x;
    int lane = tid & 63, wave = tid >> 6;
    int wm = wave >> 1, wn = wave & 1;
    int m0 = mb * 128, n0 = nb * 128;
    int l15 = lane & 15, quad = lane >> 4;

    int r0   = wave * 16 + (lane >> 2);
    int coff = (lane & 3) * 8;
    const f16* ag0 = A + (u64)(m0 + r0) * K + coff;
    const f16* ag1 = A + (u64)(m0 + r0 + 64) * K + coff;
    bool av0 = (m0 + r0) < BS, av1 = (m0 + r0 + 64) < BS;
    const f16* bg0 = Bt + (u64)(n0 + r0) * K + coff;
    const f16* bg1 = Bt + (u64)(n0 + r0 + 64) * K + coff;
    int lofs = wave * 1024;

    f32x4 acc[4][4];
#pragma unroll
    for (int i = 0; i < 4; i++)
#pragma unroll
        for (int j = 0; j < 4; j++)
#pragma unroll
            for (int r = 0; r < 4; r++) acc[i][j][r] = 0.f;

    if (av0) __builtin_amdgcn_global_load_lds((const AS1 void*)ag0, (AS3 void*)((AS3 char*)&As[0][0] + lofs), 16, 0, 0);
    if (av1) __builtin_amdgcn_global_load_lds((const AS1 void*)ag1, (AS3 void*)((AS3 char*)&As[0][0] + lofs + 4096), 16, 0, 0);
    __builtin_amdgcn_global_load_lds((const AS1 void*)bg0, (AS3 void*)((AS3 char*)&Bs[0][0] + lofs), 16, 0, 0);
    __builtin_amdgcn_global_load_lds((const AS1 void*)bg1, (AS3 void*)((AS3 char*)&Bs[0][0] + lofs + 4096), 16, 0, 0);
    ag0 += 32; ag1 += 32; bg0 += 32; bg1 += 32;

    int nit = K >> 5;
    for (int it = 0; it < nit; it++) {
        __syncthreads();
        int buf = it & 1;
        if (it + 1 < nit) {
            int nb2 = buf ^ 1;
            if (av0) __builtin_amdgcn_global_load_lds((const AS1 void*)ag0, (AS3 void*)((AS3 char*)&As[nb2][0] + lofs), 16, 0, 0);
            if (av1) __builtin_amdgcn_global_load_lds((const AS1 void*)ag1, (AS3 void*)((AS3 char*)&As[nb2][0] + lofs + 4096), 16, 0, 0);
            __builtin_amdgcn_global_load_lds((const AS1 void*)bg0, (AS3 void*)((AS3 char*)&Bs[nb2][0] + lofs), 16, 0, 0);
            __builtin_amdgcn_global_load_lds((const AS1 void*)bg1, (AS3 void*)((AS3 char*)&Bs[nb2][0] + lofs + 4096), 16, 0, 0);
            ag0 += 32; ag1 += 32; bg0 += 32; bg1 += 32;
        }
        f16x8 af[4], bf[4];
#pragma unroll
        for (int i = 0; i < 4; i++)
            af[i] = *(const f16x8*)(&As[buf][(wm * 64 + i * 16 + l15) * 32 + quad * 8]);
#pragma unroll
        for (int j = 0; j < 4; j++)
            bf[j] = *(const f16x8*)(&Bs[buf][(wn * 64 + j * 16 + l15) * 32 + quad * 8]);
#pragma unroll
        for (int i = 0; i < 4; i++)
#pragma unroll
            for (int j = 0; j < 4; j++)
                acc[i][j] = __builtin_amdgcn_mfma_f32_16x16x32_f16(af[i], bf[j], acc[i][j], 0, 0, 0);
    }

#pragma unroll
    for (int i = 0; i < 4; i++) {
#pragma unroll
        for (int j = 0; j < 4; j++) {
            int col = n0 + wn * 64 + j * 16 + l15;
            float bv = bias[col];
#pragma unroll
            for (int r = 0; r < 4; r++) {
                int row = m0 + wm * 64 + i * 16 + quad * 4 + r;
                if (row < BS) {
                    float v = acc[i][j][r] + bv;
                    if (GELU) {
                        float u = 0.7978845608028654f * (v + 0.044715f * v * v * v);
                        float e = __builtin_exp2f(-2.885390081777927f * u);
                        v = v / (1.f + e);
                    }
                    if (RESID) v += resid[(u64)row * NOUT + col];
                    if (OUTF16) Ch[(u64)row * NOUT + col] = (f16)v;
                    else        Cf[(u64)row * NOUT + col] = v;
                }
            }
        }
    }
}

// ---------------- GEMM v6.2: 256x256 8-phase pipeline, AS3-explicit LDS reads ----------------
// Round-2 post-mortem: SQ_LDS_BANK_CONFLICT == 0.0 exactly (v5 shows 7.3M) + 4x-too-slow
// phases -> fragment reads likely compiled to FLAT loads (generic `const char*` defeated
// InferAddressSpaces), which also count against vmcnt, so vmcnt(4) serialized every phase
// on full load latency. Fix: all LDS fragment reads through explicit addrspace(3) pointers.
// Also: MFMA cluster reordered into two independent sweeps (dep distance 8, not 2), and
// grid=256 with chain stride 256 (= 0 mod 8: XCD-stable mb%8 per block).
template <int NOUT, bool GELU>
__global__ __launch_bounds__(512, 2) void gemm256_kernel(const f16* __restrict__ A,
                                                         const f16* __restrict__ Bt,
                                                         const float* __restrict__ bias,
                                                         f16* __restrict__ Ch,
                                                         int K, int ntiles) {
    __shared__ __align__(16) f16 lds[2][2][16384];
    int tid = threadIdx.x;
    int lane = tid & 63, wave = tid >> 6;
    int pm = wave >> 2, pn = wave & 3;
    int l15 = lane & 15, quad = lane >> 4;
    int s7 = l15 & 7;
    int g0 = (quad ^ s7) << 4;           // byte offset of swizzled granule, kk=0
    int g1 = ((quad ^ s7) ^ 4) << 4;     // kk=1
    int rbA = (pm * 64 + l15) * 128;     // byte row base within A tile (qm=0)
    int rbB = (pn * 32 + l15) * 128;
    int srow8 = (wave << 3) + (lane >> 3);
    u64 sgel = (u64)(((lane & 7) ^ (lane >> 3)) << 3);

  for (int tix = blockIdx.x; tix < ntiles; tix += gridDim.x) {
    int mb = tix % MBP256, nb = tix / MBP256;
    if (mb >= MB256) continue;
    int m0 = mb * 256, n0 = nb * 256;

    u64 offA[4], offB[4];                // element offsets per (half,q)
#pragma unroll
    for (int i = 0; i < 4; i++) {
        int ra = m0 + i * 64 + srow8; if (ra > BS - 1) ra = BS - 1;   // clamp M tail
        offA[i] = (u64)ra * K + sgel;
        offB[i] = (u64)(n0 + i * 64 + srow8) * K + sgel;
    }

#define STAGE_A(BUF, HALF, KT) { \
    AS3 char* _d = (AS3 char*)&lds[BUF][0][0] + (HALF) * 16384 + wave * 1024; \
    __builtin_amdgcn_global_load_lds((const AS1 void*)(A + offA[(HALF) * 2]     + (u64)(KT) * 64), (AS3 void*)_d, 16, 0, 0); \
    __builtin_amdgcn_global_load_lds((const AS1 void*)(A + offA[(HALF) * 2 + 1] + (u64)(KT) * 64), (AS3 void*)(_d + 8192), 16, 0, 0); \
}
#define STAGE_B(BUF, HALF, KT) { \
    AS3 char* _d = (AS3 char*)&lds[BUF][1][0] + (HALF) * 16384 + wave * 1024; \
    __builtin_amdgcn_global_load_lds((const AS1 void*)(Bt + offB[(HALF) * 2]     + (u64)(KT) * 64), (AS3 void*)_d, 16, 0, 0); \
    __builtin_amdgcn_global_load_lds((const AS1 void*)(Bt + offB[(HALF) * 2 + 1] + (u64)(KT) * 64), (AS3 void*)(_d + 8192), 16, 0, 0); \
}
#define PH_READ_A(QM) { \
    _Pragma("unroll") for (int im = 0; im < 4; im++) { \
        af[im][0] = *(const AS3 f16x8*)(Ap + (QM) * 16384 + rbA + im * 2048 + g0); \
        af[im][1] = *(const AS3 f16x8*)(Ap + (QM) * 16384 + rbA + im * 2048 + g1); \
    } }
#define PH_READ_B(QN) { \
    _Pragma("unroll") for (int jn = 0; jn < 2; jn++) { \
        bf[jn][0] = *(const AS3 f16x8*)(Bp + (QN) * 16384 + rbB + jn * 2048 + g0); \
        bf[jn][1] = *(const AS3 f16x8*)(Bp + (QN) * 16384 + rbB + jn * 2048 + g1); \
    } }
#define PH_MMA(QM, QN) { \
    __builtin_amdgcn_s_setprio(1); \
    _Pragma("unroll") for (int im = 0; im < 4; im++) \
    _Pragma("unroll") for (int jn = 0; jn < 2; jn++) \
        acc[QM][QN][im][jn] = __builtin_amdgcn_mfma_f32_16x16x32_f16(af[im][0], bf[jn][0], acc[QM][QN][im][jn], 0, 0, 0); \
    _Pragma("unroll") for (int im = 0; im < 4; im++) \
    _Pragma("unroll") for (int jn = 0; jn < 2; jn++) \
        acc[QM][QN][im][jn] = __builtin_amdgcn_mfma_f32_16x16x32_f16(af[im][1], bf[jn][1], acc[QM][QN][im][jn], 0, 0, 0); \
    __builtin_amdgcn_s_setprio(0); \
}

    f32x4 acc[2][2][4][2];
#pragma unroll
    for (int a = 0; a < 2; a++)
#pragma unroll
        for (int b = 0; b < 2; b++)
#pragma unroll
            for (int c = 0; c < 4; c++)
#pragma unroll
                for (int d = 0; d < 2; d++)
#pragma unroll
                    for (int r = 0; r < 4; r++) acc[a][b][c][d][r] = 0.f;
    f16x8 af[4][2], bf[2][2];

    int nk = K >> 6;   // K-tiles of 64 (requires nk >= 2; K=768 -> 12)
    // prologue: tile 0 complete + tile 1's A0,B1 (the "(k-1).P3/P4" slots for k=0)
    STAGE_A(0, 0, 0); STAGE_B(0, 0, 0); STAGE_A(0, 1, 0); STAGE_B(0, 1, 0);
    STAGE_A(1, 0, 1); STAGE_B(1, 1, 1);
    asm volatile("s_waitcnt vmcnt(4)");   // tile 0's 8 loads landed, 4 in flight
    __builtin_amdgcn_s_barrier();

    for (int kt = 0; kt < nk; kt++) {
        int buf = kt & 1, bufn = buf ^ 1;
        const AS3 char* Ap = (const AS3 char*)&lds[buf][0][0];
        const AS3 char* Bp = (const AS3 char*)&lds[buf][1][0];
        bool s1 = (kt + 1 < nk), s2 = (kt + 2 < nk);
        // P1: quadrant (0,0); stage A1(kt+1)
        PH_READ_A(0); PH_READ_B(0);
        if (s1) STAGE_A(bufn, 1, kt + 1);
        __builtin_amdgcn_s_barrier();
        PH_MMA(0, 0);
        __builtin_amdgcn_s_barrier();
        // P2: quadrant (0,1); stage B0(kt+1)
        PH_READ_B(1);
        if (s1) STAGE_B(bufn, 0, kt + 1);
        __builtin_amdgcn_s_barrier();
        PH_MMA(0, 1);
        __builtin_amdgcn_s_barrier();
        // P3: quadrant (1,1); stage A0(kt+2)
        PH_READ_A(1);
        if (s2) STAGE_A(buf, 0, kt + 2);
        __builtin_amdgcn_s_barrier();
        PH_MMA(1, 1);
        __builtin_amdgcn_s_barrier();
        // P4: quadrant (1,0); stage B1(kt+2); counted vmcnt keeps 4 loads in flight
        PH_READ_B(0);
        if (s2) STAGE_B(buf, 1, kt + 2);
        if (s2) { asm volatile("s_waitcnt vmcnt(4)"); }
        else    { asm volatile("s_waitcnt vmcnt(0)"); }
        __builtin_amdgcn_s_barrier();
        PH_MMA(1, 0);
        __builtin_amdgcn_s_barrier();
    }

    // epilogue
    int quad4 = quad << 2;
#pragma unroll
    for (int qn = 0; qn < 2; qn++)
#pragma unroll
        for (int jn = 0; jn < 2; jn++) {
            int col = n0 + qn * 128 + pn * 32 + jn * 16 + l15;
            float bv = bias[col];
#pragma unroll
            for (int qm = 0; qm < 2; qm++)
#pragma unroll
                for (int im = 0; im < 4; im++) {
                    int rowb = m0 + qm * 128 + pm * 64 + im * 16 + quad4;
#pragma unroll
                    for (int r = 0; r < 4; r++) {
                        int row = rowb + r;
                        if (row < BS) {
                            float v = acc[qm][qn][im][jn][r] + bv;
                            if (GELU) {
                                float u = 0.7978845608028654f * (v + 0.044715f * v * v * v);
                                float e = __builtin_exp2f(-2.885390081777927f * u);
                                v = v / (1.f + e);
                            }
                            Ch[(u64)row * NOUT + col] = (f16)v;
                        }
                    }
                }
        }
#undef STAGE_A
#undef STAGE_B
#undef PH_READ_A
#undef PH_READ_B
#undef PH_MMA
  }
}

// ---------------- time attention: wave per (b,h,p); 8 queries x 9 keys ----------------
__global__ __launch_bounds__(256) void time_attn_kernel(const f16* __restrict__ qkv,
                                                        f16* __restrict__ ctx) {
    int w = blockIdx.x * 4 + (threadIdx.x >> 6);
    int lane = threadIdx.x & 63;
    int b = w / (NH * PP);
    int rem = w % (NH * PP);
    int h = rem / PP, p = rem % PP;
    u64 bb = (u64)b * SQ;
    int hoff = h * 64 + lane;

    float qv[TT], kv[9], vv[9];
#pragma unroll
    for (int t = 0; t < TT; t++) qv[t] = (float)qkv[(bb + 1 + t * PP + p) * QKVN + hoff];
    kv[0] = (float)qkv[bb * QKVN + 768 + hoff];
    vv[0] = (float)qkv[bb * QKVN + 1536 + hoff];
#pragma unroll
    for (int j = 1; j <= TT; j++) {
        u64 ro = (bb + 1 + (u64)(j - 1) * PP + p) * QKVN;
        kv[j] = (float)qkv[ro + 768 + hoff];
        vv[j] = (float)qkv[ro + 1536 + hoff];
    }
#pragma unroll
    for (int t = 0; t < TT; t++) {
        float s[9];
#pragma unroll
        for (int j = 0; j < 9; j++) {
            float ps = qv[t] * kv[j];
#pragma unroll
            for (int m = 1; m < 64; m <<= 1) ps += __shfl_xor(ps, m, 64);
            s[j] = ps * 0.125f;
        }
        float mx = s[0];
#pragma unroll
        for (int j = 1; j < 9; j++) mx = fmaxf(mx, s[j]);
        float sum = 0.f;
#pragma unroll
        for (int j = 0; j < 9; j++) { s[j] = expf(s[j] - mx); sum += s[j]; }
        float o = 0.f;
#pragma unroll
        for (int j = 0; j < 9; j++) o += s[j] * vv[j];
        o /= sum;
        ctx[(bb + 1 + (u64)t * PP + p) * DM + h * 64 + lane] = (f16)o;
    }
}

// ---------------- CLS attention split-K: part kernel, block per (b,h,chunk) ----------------
__global__ __launch_bounds__(256) void cls_part_kernel(const f16* __restrict__ qkv,
                                                       float* __restrict__ part) {
    int g = blockIdx.x;
    int c = g % CCH, bh = g / CCH;
    int b = bh / NH, h = bh % NH;
    u64 bb = (u64)b * SQ;
    int tid = threadIdx.x, lane = tid & 63, wave = tid >> 6;
    __shared__ float sc[CKEY];
    __shared__ float accbuf[4][64];
    __shared__ float lbuf[4];
    __shared__ float mxs;
    float qd = (float)qkv[bb * QKVN + h * 64 + lane];
    int j0 = c * CKEY;
    int cnt = SQ - j0; if (cnt > CKEY) cnt = CKEY;
    for (int jj = wave; jj < cnt; jj += 4) {
        float p = qd * (float)qkv[(bb + j0 + jj) * QKVN + 768 + h * 64 + lane];
#pragma unroll
        for (int m = 1; m < 64; m <<= 1) p += __shfl_xor(p, m, 64);
        if (lane == 0) sc[jj] = p * 0.125f;
    }
    __syncthreads();
    if (wave == 0) {
        float m = -1e30f;
        for (int j = lane; j < cnt; j += 64) m = fmaxf(m, sc[j]);
#pragma unroll
        for (int s = 1; s < 64; s <<= 1) m = fmaxf(m, __shfl_xor(m, s, 64));
        if (lane == 0) mxs = m;
    }
    __syncthreads();
    float mx = mxs;
    float acc = 0.f, l = 0.f;
    for (int jj = wave; jj < cnt; jj += 4) {
        float w = expf(sc[jj] - mx);
        l += w;
        acc += w * (float)qkv[(bb + j0 + jj) * QKVN + 1536 + h * 64 + lane];
    }
    accbuf[wave][lane] = acc;
    if (lane == 0) lbuf[wave] = l;
    __syncthreads();
    if (tid < 64) {
        float a = accbuf[0][tid] + accbuf[1][tid] + accbuf[2][tid] + accbuf[3][tid];
        float* pb = part + ((u64)bh * CCH + c) * 66;
        if (tid == 0) { pb[0] = mxs; pb[1] = lbuf[0] + lbuf[1] + lbuf[2] + lbuf[3]; }
        pb[2 + tid] = a;
    }
}

// ---------------- CLS attention split-K: combine kernel, wave per (b,h) ----------------
__global__ __launch_bounds__(256) void cls_comb_kernel(const float* __restrict__ part,
                                                       f16* __restrict__ ctx) {
    int w = blockIdx.x * 4 + (threadIdx.x >> 6);
    int lane = threadIdx.x & 63;
    if (w >= BQ * NH) return;
    int b = w / NH, h = w % NH;
    const float* pb = part + (u64)w * CCH * 66;
    float m = (lane < CCH) ? pb[lane * 66] : -1e30f;
#pragma unroll
    for (int s = 1; s < 64; s <<= 1) m = fmaxf(m, __shfl_xor(m, s, 64));
    float l = (lane < CCH) ? pb[lane * 66 + 1] * expf(pb[lane * 66] - m) : 0.f;
#pragma unroll
    for (int s = 1; s < 64; s <<= 1) l += __shfl_xor(l, s, 64);
    float o = 0.f;
    for (int j = 0; j < CCH; j++) {
        float mj = pb[j * 66];
        o += pb[j * 66 + 2 + lane] * expf(mj - m);
    }
    ctx[((u64)b * SQ) * DM + h * 64 + lane] = (f16)(o / l);
}

// ---------------- space attention: MFMA flash, block per (b,h,t) ----------------
__global__ __launch_bounds__(256) void space_attn_kernel(const f16* __restrict__ qkv,
                                                         f16* __restrict__ ctx) {
    int g = blockIdx.x;
    int b = g / (NH * TT);
    int rem = g % (NH * TT);
    int h = rem / TT, t = rem % TT;
    __shared__ __align__(16) f16 Vt[64 * 232];
    __shared__ __align__(16) f16 Ps[4 * 16 * 232];
    u64 bb = (u64)b * SQ;
    int tid = threadIdx.x, lane = tid & 63, wave = tid >> 6;
    int l15 = lane & 15, quad = lane >> 4;

    for (int i = tid; i < 4 * 16 * 232 * 2 / 16; i += 256)
        ((uint4*)Ps)[i] = make_uint4(0u, 0u, 0u, 0u);

    for (int idx = tid; idx < 232 * 8; idx += 256) {
        int c8 = idx / 232;
        int j  = idx - c8 * 232;
        int c  = c8 * 8;
        uint4 vraw = make_uint4(0u, 0u, 0u, 0u);
        if (j < 197) {
            int tok = (j == 0) ? 0 : (1 + t * PP + (j - 1));
            vraw = *(const uint4*)(qkv + (bb + tok) * QKVN + 1536 + h * 64 + c);
        }
        f16x8 vv = *(f16x8*)&vraw;
#pragma unroll
        for (int e = 0; e < 8; e++) Vt[(c + e) * 232 + j] = vv[e];
    }
    __syncthreads();

    f16* myP = Ps + wave * 16 * 232;
    for (int qt = wave; qt < 13; qt += 4) {
        int mloc = qt * 16 + l15;
        int mc = mloc > 195 ? 195 : mloc;
        const f16* qr = qkv + (bb + 1 + (u64)t * PP + mc) * QKVN + h * 64;
        f16x8 qa0 = *(const f16x8*)(qr + quad * 8);
        f16x8 qa1 = *(const f16x8*)(qr + 32 + quad * 8);

        f32x4 s[13];
#pragma unroll
        for (int nt = 0; nt < 13; nt++) { s[nt][0] = 0.f; s[nt][1] = 0.f; s[nt][2] = 0.f; s[nt][3] = 0.f; }
#pragma unroll
        for (int nt = 0; nt < 13; nt++) {
            int n = nt * 16 + l15;
            int ncl = n > 196 ? 196 : n;
            int tok = (ncl == 0) ? 0 : (1 + t * PP + (ncl - 1));
            const f16* kr = qkv + (bb + tok) * QKVN + 768 + h * 64;
            f16x8 kb0 = *(const f16x8*)(kr + quad * 8);
            f16x8 kb1 = *(const f16x8*)(kr + 32 + quad * 8);
            s[nt] = __builtin_amdgcn_mfma_f32_16x16x32_f16(qa0, kb0, s[nt], 0, 0, 0);
            s[nt] = __builtin_amdgcn_mfma_f32_16x16x32_f16(qa1, kb1, s[nt], 0, 0, 0);
        }
        if (l15 >= 5) { s[12][0] = -1e30f; s[12][1] = -1e30f; s[12][2] = -1e30f; s[12][3] = -1e30f; }

        float mx[4] = {-1e30f, -1e30f, -1e30f, -1e30f};
#pragma unroll
        for (int nt = 0; nt < 13; nt++)
#pragma unroll
            for (int r = 0; r < 4; r++) mx[r] = fmaxf(mx[r], s[nt][r]);
#pragma unroll
        for (int m = 1; m < 16; m <<= 1)
#pragma unroll
            for (int r = 0; r < 4; r++) mx[r] = fmaxf(mx[r], __shfl_xor(mx[r], m, 64));

        float sum[4] = {0.f, 0.f, 0.f, 0.f};
#pragma unroll
        for (int nt = 0; nt < 13; nt++)
#pragma unroll
            for (int r = 0; r < 4; r++) {
                float p = exp2f((s[nt][r] - mx[r]) * 0.18033688011112042f);
                s[nt][r] = p;
                sum[r] += p;
            }
#pragma unroll
        for (int m = 1; m < 16; m <<= 1)
#pragma unroll
            for (int r = 0; r < 4; r++) sum[r] += __shfl_xor(sum[r], m, 64);

#pragma unroll
        for (int nt = 0; nt < 13; nt++)
#pragma unroll
            for (int r = 0; r < 4; r++)
                myP[(quad * 4 + r) * 232 + nt * 16 + l15] = (f16)s[nt][r];

        f32x4 o[4];
#pragma unroll
        for (int n2 = 0; n2 < 4; n2++) { o[n2][0] = 0.f; o[n2][1] = 0.f; o[n2][2] = 0.f; o[n2][3] = 0.f; }
#pragma unroll
        for (int kc = 0; kc < 7; kc++) {
            f16x8 pa = *(const f16x8*)(&myP[l15 * 232 + kc * 32 + quad * 8]);
#pragma unroll
            for (int n2 = 0; n2 < 4; n2++) {
                f16x8 vb = *(const f16x8*)(&Vt[(n2 * 16 + l15) * 232 + kc * 32 + quad * 8]);
                o[n2] = __builtin_amdgcn_mfma_f32_16x16x32_f16(pa, vb, o[n2], 0, 0, 0);
            }
        }

        float inv[4];
#pragma unroll
        for (int r = 0; r < 4; r++) inv[r] = 1.f / sum[r];
#pragma unroll
        for (int n2 = 0; n2 < 4; n2++)
#pragma unroll
            for (int r = 0; r < 4; r++) {
                int m = qt * 16 + quad * 4 + r;
                if (m < PP)
                    ctx[(bb + 1 + (u64)t * PP + m) * DM + h * 64 + n2 * 16 + l15] = (f16)(o[n2][r] * inv[r]);
            }
    }
}

// ---------------- host ----------------
extern "C" void kernel_launch(void* const* d_in, const int* in_sizes, int n_in,
                              void* d_out, int out_size, void* d_ws, size_t ws_size,
                              hipStream_t stream) {
    const float* x_in  = (const float*)d_in[0];
    const float* t_Wq  = (const float*)d_in[1];
    const float* t_bq  = (const float*)d_in[2];
    const float* t_Wk  = (const float*)d_in[3];
    const float* t_bk  = (const float*)d_in[4];
    const float* t_Wv  = (const float*)d_in[5];
    const float* t_bv  = (const float*)d_in[6];
    const float* t_Wo  = (const float*)d_in[7];
    const float* t_bo  = (const float*)d_in[8];
    const float* s_Wq  = (const float*)d_in[9];
    const float* s_bq  = (const float*)d_in[10];
    const float* s_Wk  = (const float*)d_in[11];
    const float* s_bk  = (const float*)d_in[12];
    const float* s_Wv  = (const float*)d_in[13];
    const float* s_bv  = (const float*)d_in[14];
    const float* s_Wo  = (const float*)d_in[15];
    const float* s_bo  = (const float*)d_in[16];
    const float* W1    = (const float*)d_in[17];
    const float* b1    = (const float*)d_in[18];
    const float* W2    = (const float*)d_in[19];
    const float* b2    = (const float*)d_in[20];
    const float* ln1g  = (const float*)d_in[21];
    const float* ln1b  = (const float*)d_in[22];
    const float* ln2g  = (const float*)d_in[23];
    const float* ln2b  = (const float*)d_in[24];
    const float* ln3g  = (const float*)d_in[25];
    const float* ln3b  = (const float*)d_in[26];

    char* ws = (char*)d_ws;
    f16* y    = (f16*)(ws + Y_OFF);
    f16* qkv  = (f16*)(ws + QKV_OFF);
    f16* ctx  = (f16*)(ws + CTX_OFF);
    f16* hbuf = (f16*)(ws + H_OFF);
    float* clsP = (float*)(ws + Y_OFF);   // reuses dead y region
    char* wreg = ws + W_OFF;
    f16* tQKV  = (f16*)(wreg);
    f16* tWoT  = (f16*)(wreg + 3538944);
    f16* sQKV  = (f16*)(wreg + 4718592);
    f16* sWoT  = (f16*)(wreg + 8257536);
    f16* W1T   = (f16*)(wreg + 9437184);
    f16* W2T   = (f16*)(wreg + 14155776);
    float* tBias = (float*)(wreg + 18874368);
    float* sBias = (float*)(wreg + 18883584);
    float* xcur  = (float*)d_out;

    dim3 tb(256);
    dim3 tb512(512);
    // --- weight prep ---
    transpose_kernel<<<dim3(24, 24), tb, 0, stream>>>(t_Wq, tQKV, 768, 768);
    transpose_kernel<<<dim3(24, 24), tb, 0, stream>>>(t_Wk, tQKV + 768 * 768, 768, 768);
    transpose_kernel<<<dim3(24, 24), tb, 0, stream>>>(t_Wv, tQKV + 2 * 768 * 768, 768, 768);
    transpose_kernel<<<dim3(24, 24), tb, 0, stream>>>(t_Wo, tWoT, 768, 768);
    transpose_kernel<<<dim3(24, 24), tb, 0, stream>>>(s_Wq, sQKV, 768, 768);
    transpose_kernel<<<dim3(24, 24), tb, 0, stream>>>(s_Wk, sQKV + 768 * 768, 768, 768);
    transpose_kernel<<<dim3(24, 24), tb, 0, stream>>>(s_Wv, sQKV + 2 * 768 * 768, 768, 768);
    transpose_kernel<<<dim3(24, 24), tb, 0, stream>>>(s_Wo, sWoT, 768, 768);
    transpose_kernel<<<dim3(96, 24), tb, 0, stream>>>(W1, W1T, 768, 3072);
    transpose_kernel<<<dim3(24, 96), tb, 0, stream>>>(W2, W2T, 3072, 768);
    bias3_kernel<<<3, tb, 0, stream>>>(t_bq, t_bk, t_bv, tBias);
    bias3_kernel<<<3, tb, 0, stream>>>(s_bq, s_bk, s_bv, sBias);

    // --- phase A: time MHA ---
    ln_kernel<<<3138, tb, 0, stream>>>(x_in, ln1g, ln1b, y);
    gemm256_kernel<QKVN, false><<<256, tb512, 0, stream>>>(y, tQKV, tBias, qkv, 768, MBP256 * 9);
    time_attn_kernel<<<4704, tb, 0, stream>>>(qkv, ctx);
    cls_part_kernel<<<BQ * NH * CCH, tb, 0, stream>>>(qkv, clsP);
    cls_comb_kernel<<<24, tb, 0, stream>>>(clsP, ctx);
    gemm_kernel<DM, false, true, false><<<MB_PAD * 6, tb, 0, stream>>>(ctx, tWoT, t_bo, x_in, xcur, nullptr, 768);

    // --- phase B: space MHA ---
    ln_kernel<<<3138, tb, 0, stream>>>(xcur, ln2g, ln2b, y);
    gemm256_kernel<QKVN, false><<<256, tb512, 0, stream>>>(y, sQKV, sBias, qkv, 768, MBP256 * 9);
    space_attn_kernel<<<768, tb, 0, stream>>>(qkv, ctx);
    cls_part_kernel<<<BQ * NH * CCH, tb, 0, stream>>>(qkv, clsP);
    cls_comb_kernel<<<24, tb, 0, stream>>>(clsP, ctx);
    gemm_kernel<DM, false, true, false><<<MB_PAD * 6, tb, 0, stream>>>(ctx, sWoT, s_bo, xcur, xcur, nullptr, 768);

    // --- phase C: MLP ---
    ln_kernel<<<3138, tb, 0, stream>>>(xcur, ln3g, ln3b, y);
    gemm256_kernel<D4, true><<<256, tb512, 0, stream>>>(y, W1T, b1, hbuf, 768, MBP256 * 12);
    gemm_kernel<DM, false, true, false><<<MB_PAD * 6, tb, 0, stream>>>(hbuf, W2T, b2, xcur, xcur, nullptr, 3072);
}

// Round 4
// 880.683 us; speedup vs baseline: 1.0347x; 1.0151x over previous
//
#include <hip/hip_runtime.h>

// ---------------- problem constants ----------------
#define BQ   8
#define SQ   1569
#define BS   12552      // BQ*SQ
#define DM   768
#define NH   12
#define DH   64
#define TT   8
#define PP   196
#define D4   3072
#define QKVN 2304
#define CCH  24         // CLS split-K chunks
#define CKEY 66         // keys per chunk (24*66 = 1584 >= 1569)
#define MB_PAD 104      // 99 m-blocks padded to multiple of 8 for XCD-stable swizzle

typedef _Float16 f16;
typedef _Float16 f16x8 __attribute__((ext_vector_type(8)));
typedef float    f32x4 __attribute__((ext_vector_type(4)));
typedef unsigned long long u64;

#define AS1 __attribute__((address_space(1)))
#define AS3 __attribute__((address_space(3)))

#define Y_OFF    0ULL
#define QKV_OFF  19279872ULL
#define CTX_OFF  77119488ULL
#define H_OFF    19279872ULL
#define W_OFF    96399360ULL

// ---------------- LayerNorm (wave per row) ----------------
__global__ __launch_bounds__(256) void ln_kernel(const float* __restrict__ x,
                                                 const float* __restrict__ g,
                                                 const float* __restrict__ bta,
                                                 f16* __restrict__ y) {
    int row = blockIdx.x * 4 + (threadIdx.x >> 6);
    int lane = threadIdx.x & 63;
    if (row >= BS) return;
    const float* xr = x + (u64)row * DM;
    float v[12];
    float s = 0.f, s2 = 0.f;
#pragma unroll
    for (int i = 0; i < 12; i++) { v[i] = xr[lane + i * 64]; s += v[i]; s2 += v[i] * v[i]; }
#pragma unroll
    for (int m = 1; m < 64; m <<= 1) { s += __shfl_xor(s, m, 64); s2 += __shfl_xor(s2, m, 64); }
    float mean = s * (1.f / 768.f);
    float var  = s2 * (1.f / 768.f) - mean * mean;
    float rstd = rsqrtf(var + 1e-12f);
    f16* yr = y + (u64)row * DM;
#pragma unroll
    for (int i = 0; i < 12; i++) {
        int c = lane + i * 64;
        yr[c] = (f16)((v[i] - mean) * rstd * g[c] + bta[c]);
    }
}

// ---------------- transpose fp32 -> f16 (dst[c*R+r] = src[r*C+c]) ----------------
__global__ __launch_bounds__(256) void transpose_kernel(const float* __restrict__ src,
                                                        f16* __restrict__ dst,
                                                        int R, int C) {
    __shared__ float tile[32][33];
    int bx = blockIdx.x * 32;
    int by = blockIdx.y * 32;
    int tx = threadIdx.x & 31, ty = threadIdx.x >> 5;
#pragma unroll
    for (int i = 0; i < 4; i++) {
        int r = by + ty + i * 8, c = bx + tx;
        if (r < R && c < C) tile[ty + i * 8][tx] = src[(u64)r * C + c];
    }
    __syncthreads();
#pragma unroll
    for (int i = 0; i < 4; i++) {
        int c = bx + ty + i * 8, r = by + tx;
        if (c < C && r < R) dst[(u64)c * R + r] = (f16)tile[tx][ty + i * 8];
    }
}

// ---------------- concat 3 bias vectors (768 each) ----------------
__global__ __launch_bounds__(256) void bias3_kernel(const float* __restrict__ a,
                                                    const float* __restrict__ b,
                                                    const float* __restrict__ c,
                                                    float* __restrict__ dst) {
    int i = blockIdx.x * 256 + threadIdx.x;
    if (i < 768) { dst[i] = a[i]; dst[i + 768] = b[i]; dst[i + 1536] = c[i]; }
}

// ---------------- GEMM v5.1: R4 staging + 1-barrier dbuf + 5-block occupancy ----------------
// C = A(BSxK,f16) @ Bt^T (Bt NxK f16) + bias [+gelu][+resid]
// Grid: id = nb*MB_PAD + mb (mb fastest -> id%8 == mb%8, XCD-stable A slices).
// __launch_bounds__(256,5): 32 KB LDS/block allows 5 blocks/CU (5x32=160KB);
// VGPR cap 102 >> 56 used, so no spill. One extra block of TLP hides the
// per-iteration barrier drain (m114 mechanism). If only 4 fit, behavior == v5.
// NOTE (rounds 1-3): an 8-phase 256^2 port of the HK template was tried and
// reverted — it ran 4x under its cycle model (~13k cyc/K-tile vs ~3.5k) with
// MfmaUtil 16% and could not be diagnosed from counters alone.
template <int NOUT, bool GELU, bool RESID, bool OUTF16>
__global__ __launch_bounds__(256, 5) void gemm_kernel(const f16* __restrict__ A,
                                                      const f16* __restrict__ Bt,
                                                      const float* __restrict__ bias,
                                                      const float* __restrict__ resid,
                                                      float* __restrict__ Cf,
                                                      f16* __restrict__ Ch,
                                                      int K) {
    __shared__ __align__(16) f16 As[2][128 * 32];
    __shared__ __align__(16) f16 Bs[2][128 * 32];
    int id = blockIdx.x;
    int mb = id % MB_PAD, nb = id / MB_PAD;
    if (mb >= 99) return;
    int tid  = threadIdx.x;
    int lane = tid & 63, wave = tid >> 6;
    int wm = wave >> 1, wn = wave & 1;
    int m0 = mb * 128, n0 = nb * 128;
    int l15 = lane & 15, quad = lane >> 4;

    // staging addressing (R4): wave w stages rows w*16+(lane>>2) (+64 for half 1),
    // 8-f16 chunk (lane&3); LDS byte = wave*1024 + lane*16 (+4096)
    int r0   = wave * 16 + (lane >> 2);
    int coff = (lane & 3) * 8;
    const f16* ag0 = A + (u64)(m0 + r0) * K + coff;
    const f16* ag1 = A + (u64)(m0 + r0 + 64) * K + coff;
    bool av0 = (m0 + r0) < BS, av1 = (m0 + r0 + 64) < BS;
    const f16* bg0 = Bt + (u64)(n0 + r0) * K + coff;
    const f16* bg1 = Bt + (u64)(n0 + r0 + 64) * K + coff;
    int lofs = wave * 1024;

    f32x4 acc[4][4];
#pragma unroll
    for (int i = 0; i < 4; i++)
#pragma unroll
        for (int j = 0; j < 4; j++)
#pragma unroll
            for (int r = 0; r < 4; r++) acc[i][j][r] = 0.f;

    // prologue: stage tile 0 into buffer 0
    if (av0) __builtin_amdgcn_global_load_lds((const AS1 void*)ag0, (AS3 void*)((AS3 char*)&As[0][0] + lofs), 16, 0, 0);
    if (av1) __builtin_amdgcn_global_load_lds((const AS1 void*)ag1, (AS3 void*)((AS3 char*)&As[0][0] + lofs + 4096), 16, 0, 0);
    __builtin_amdgcn_global_load_lds((const AS1 void*)bg0, (AS3 void*)((AS3 char*)&Bs[0][0] + lofs), 16, 0, 0);
    __builtin_amdgcn_global_load_lds((const AS1 void*)bg1, (AS3 void*)((AS3 char*)&Bs[0][0] + lofs + 4096), 16, 0, 0);
    ag0 += 32; ag1 += 32; bg0 += 32; bg1 += 32;

    int nit = K >> 5;
    for (int it = 0; it < nit; it++) {
        __syncthreads();                 // drains staging for buffer it&1
        int buf = it & 1;
        if (it + 1 < nit) {              // prefetch next tile into other buffer
            int nb2 = buf ^ 1;
            if (av0) __builtin_amdgcn_global_load_lds((const AS1 void*)ag0, (AS3 void*)((AS3 char*)&As[nb2][0] + lofs), 16, 0, 0);
            if (av1) __builtin_amdgcn_global_load_lds((const AS1 void*)ag1, (AS3 void*)((AS3 char*)&As[nb2][0] + lofs + 4096), 16, 0, 0);
            __builtin_amdgcn_global_load_lds((const AS1 void*)bg0, (AS3 void*)((AS3 char*)&Bs[nb2][0] + lofs), 16, 0, 0);
            __builtin_amdgcn_global_load_lds((const AS1 void*)bg1, (AS3 void*)((AS3 char*)&Bs[nb2][0] + lofs + 4096), 16, 0, 0);
            ag0 += 32; ag1 += 32; bg0 += 32; bg1 += 32;
        }
        f16x8 af[4], bf[4];
#pragma unroll
        for (int i = 0; i < 4; i++)
            af[i] = *(const f16x8*)(&As[buf][(wm * 64 + i * 16 + l15) * 32 + quad * 8]);
#pragma unroll
        for (int j = 0; j < 4; j++)
            bf[j] = *(const f16x8*)(&Bs[buf][(wn * 64 + j * 16 + l15) * 32 + quad * 8]);
#pragma unroll
        for (int i = 0; i < 4; i++)
#pragma unroll
            for (int j = 0; j < 4; j++)
                acc[i][j] = __builtin_amdgcn_mfma_f32_16x16x32_f16(af[i], bf[j], acc[i][j], 0, 0, 0);
    }

#pragma unroll
    for (int i = 0; i < 4; i++) {
#pragma unroll
        for (int j = 0; j < 4; j++) {
            int col = n0 + wn * 64 + j * 16 + l15;
            float bv = bias[col];
#pragma unroll
            for (int r = 0; r < 4; r++) {
                int row = m0 + wm * 64 + i * 16 + quad * 4 + r;
                if (row < BS) {
                    float v = acc[i][j][r] + bv;
                    if (GELU) {
                        // tanh-approx GELU (max dev ~3e-3 from exact erf form):
                        // gelu(x) = x * sigmoid(2*0.7978845608*(x + 0.044715 x^3))
                        float u = 0.7978845608028654f * (v + 0.044715f * v * v * v);
                        float e = __builtin_exp2f(-2.885390081777927f * u);
                        v = v / (1.f + e);
                    }
                    if (RESID) v += resid[(u64)row * NOUT + col];
                    if (OUTF16) Ch[(u64)row * NOUT + col] = (f16)v;
                    else        Cf[(u64)row * NOUT + col] = v;
                }
            }
        }
    }
}

// ---------------- time attention: wave per (b,h,p); 8 queries x 9 keys ----------------
__global__ __launch_bounds__(256) void time_attn_kernel(const f16* __restrict__ qkv,
                                                        f16* __restrict__ ctx) {
    int w = blockIdx.x * 4 + (threadIdx.x >> 6);
    int lane = threadIdx.x & 63;
    int b = w / (NH * PP);
    int rem = w % (NH * PP);
    int h = rem / PP, p = rem % PP;
    u64 bb = (u64)b * SQ;
    int hoff = h * 64 + lane;

    float qv[TT], kv[9], vv[9];
#pragma unroll
    for (int t = 0; t < TT; t++) qv[t] = (float)qkv[(bb + 1 + t * PP + p) * QKVN + hoff];
    kv[0] = (float)qkv[bb * QKVN + 768 + hoff];
    vv[0] = (float)qkv[bb * QKVN + 1536 + hoff];
#pragma unroll
    for (int j = 1; j <= TT; j++) {
        u64 ro = (bb + 1 + (u64)(j - 1) * PP + p) * QKVN;
        kv[j] = (float)qkv[ro + 768 + hoff];
        vv[j] = (float)qkv[ro + 1536 + hoff];
    }
#pragma unroll
    for (int t = 0; t < TT; t++) {
        float s[9];
#pragma unroll
        for (int j = 0; j < 9; j++) {
            float ps = qv[t] * kv[j];
#pragma unroll
            for (int m = 1; m < 64; m <<= 1) ps += __shfl_xor(ps, m, 64);
            s[j] = ps * 0.125f;
        }
        float mx = s[0];
#pragma unroll
        for (int j = 1; j < 9; j++) mx = fmaxf(mx, s[j]);
        float sum = 0.f;
#pragma unroll
        for (int j = 0; j < 9; j++) { s[j] = expf(s[j] - mx); sum += s[j]; }
        float o = 0.f;
#pragma unroll
        for (int j = 0; j < 9; j++) o += s[j] * vv[j];
        o /= sum;
        ctx[(bb + 1 + (u64)t * PP + p) * DM + h * 64 + lane] = (f16)o;
    }
}

// ---------------- CLS attention split-K: part kernel, block per (b,h,chunk) ----------------
__global__ __launch_bounds__(256) void cls_part_kernel(const f16* __restrict__ qkv,
                                                       float* __restrict__ part) {
    int g = blockIdx.x;
    int c = g % CCH, bh = g / CCH;
    int b = bh / NH, h = bh % NH;
    u64 bb = (u64)b * SQ;
    int tid = threadIdx.x, lane = tid & 63, wave = tid >> 6;
    __shared__ float sc[CKEY];
    __shared__ float accbuf[4][64];
    __shared__ float lbuf[4];
    __shared__ float mxs;
    float qd = (float)qkv[bb * QKVN + h * 64 + lane];
    int j0 = c * CKEY;
    int cnt = SQ - j0; if (cnt > CKEY) cnt = CKEY;
    for (int jj = wave; jj < cnt; jj += 4) {
        float p = qd * (float)qkv[(bb + j0 + jj) * QKVN + 768 + h * 64 + lane];
#pragma unroll
        for (int m = 1; m < 64; m <<= 1) p += __shfl_xor(p, m, 64);
        if (lane == 0) sc[jj] = p * 0.125f;
    }
    __syncthreads();
    if (wave == 0) {
        float m = -1e30f;
        for (int j = lane; j < cnt; j += 64) m = fmaxf(m, sc[j]);
#pragma unroll
        for (int s = 1; s < 64; s <<= 1) m = fmaxf(m, __shfl_xor(m, s, 64));
        if (lane == 0) mxs = m;
    }
    __syncthreads();
    float mx = mxs;
    float acc = 0.f, l = 0.f;
    for (int jj = wave; jj < cnt; jj += 4) {
        float w = expf(sc[jj] - mx);
        l += w;
        acc += w * (float)qkv[(bb + j0 + jj) * QKVN + 1536 + h * 64 + lane];
    }
    accbuf[wave][lane] = acc;
    if (lane == 0) lbuf[wave] = l;
    __syncthreads();
    if (tid < 64) {
        float a = accbuf[0][tid] + accbuf[1][tid] + accbuf[2][tid] + accbuf[3][tid];
        float* pb = part + ((u64)bh * CCH + c) * 66;
        if (tid == 0) { pb[0] = mxs; pb[1] = lbuf[0] + lbuf[1] + lbuf[2] + lbuf[3]; }
        pb[2 + tid] = a;
    }
}

// ---------------- CLS attention split-K: combine kernel, wave per (b,h) ----------------
__global__ __launch_bounds__(256) void cls_comb_kernel(const float* __restrict__ part,
                                                       f16* __restrict__ ctx) {
    int w = blockIdx.x * 4 + (threadIdx.x >> 6);
    int lane = threadIdx.x & 63;
    if (w >= BQ * NH) return;
    int b = w / NH, h = w % NH;
    const float* pb = part + (u64)w * CCH * 66;
    float m = (lane < CCH) ? pb[lane * 66] : -1e30f;
#pragma unroll
    for (int s = 1; s < 64; s <<= 1) m = fmaxf(m, __shfl_xor(m, s, 64));
    float l = (lane < CCH) ? pb[lane * 66 + 1] * expf(pb[lane * 66] - m) : 0.f;
#pragma unroll
    for (int s = 1; s < 64; s <<= 1) l += __shfl_xor(l, s, 64);
    float o = 0.f;
    for (int j = 0; j < CCH; j++) {
        float mj = pb[j * 66];
        o += pb[j * 66 + 2 + lane] * expf(mj - m);
    }
    ctx[((u64)b * SQ) * DM + h * 64 + lane] = (f16)(o / l);
}

// ---------------- space attention: MFMA flash, block per (b,h,t) ----------------
__global__ __launch_bounds__(256) void space_attn_kernel(const f16* __restrict__ qkv,
                                                         f16* __restrict__ ctx) {
    int g = blockIdx.x;
    int b = g / (NH * TT);
    int rem = g % (NH * TT);
    int h = rem / TT, t = rem % TT;
    __shared__ __align__(16) f16 Vt[64 * 232];
    __shared__ __align__(16) f16 Ps[4 * 16 * 232];
    u64 bb = (u64)b * SQ;
    int tid = threadIdx.x, lane = tid & 63, wave = tid >> 6;
    int l15 = lane & 15, quad = lane >> 4;

    for (int i = tid; i < 4 * 16 * 232 * 2 / 16; i += 256)
        ((uint4*)Ps)[i] = make_uint4(0u, 0u, 0u, 0u);

    for (int idx = tid; idx < 232 * 8; idx += 256) {
        int c8 = idx / 232;
        int j  = idx - c8 * 232;
        int c  = c8 * 8;
        uint4 vraw = make_uint4(0u, 0u, 0u, 0u);
        if (j < 197) {
            int tok = (j == 0) ? 0 : (1 + t * PP + (j - 1));
            vraw = *(const uint4*)(qkv + (bb + tok) * QKVN + 1536 + h * 64 + c);
        }
        f16x8 vv = *(f16x8*)&vraw;
#pragma unroll
        for (int e = 0; e < 8; e++) Vt[(c + e) * 232 + j] = vv[e];
    }
    __syncthreads();

    f16* myP = Ps + wave * 16 * 232;
    for (int qt = wave; qt < 13; qt += 4) {
        int mloc = qt * 16 + l15;
        int mc = mloc > 195 ? 195 : mloc;
        const f16* qr = qkv + (bb + 1 + (u64)t * PP + mc) * QKVN + h * 64;
        f16x8 qa0 = *(const f16x8*)(qr + quad * 8);
        f16x8 qa1 = *(const f16x8*)(qr + 32 + quad * 8);

        f32x4 s[13];
#pragma unroll
        for (int nt = 0; nt < 13; nt++) { s[nt][0] = 0.f; s[nt][1] = 0.f; s[nt][2] = 0.f; s[nt][3] = 0.f; }
#pragma unroll
        for (int nt = 0; nt < 13; nt++) {
            int n = nt * 16 + l15;
            int ncl = n > 196 ? 196 : n;
            int tok = (ncl == 0) ? 0 : (1 + t * PP + (ncl - 1));
            const f16* kr = qkv + (bb + tok) * QKVN + 768 + h * 64;
            f16x8 kb0 = *(const f16x8*)(kr + quad * 8);
            f16x8 kb1 = *(const f16x8*)(kr + 32 + quad * 8);
            s[nt] = __builtin_amdgcn_mfma_f32_16x16x32_f16(qa0, kb0, s[nt], 0, 0, 0);
            s[nt] = __builtin_amdgcn_mfma_f32_16x16x32_f16(qa1, kb1, s[nt], 0, 0, 0);
        }
        if (l15 >= 5) { s[12][0] = -1e30f; s[12][1] = -1e30f; s[12][2] = -1e30f; s[12][3] = -1e30f; }

        float mx[4] = {-1e30f, -1e30f, -1e30f, -1e30f};
#pragma unroll
        for (int nt = 0; nt < 13; nt++)
#pragma unroll
            for (int r = 0; r < 4; r++) mx[r] = fmaxf(mx[r], s[nt][r]);
#pragma unroll
        for (int m = 1; m < 16; m <<= 1)
#pragma unroll
            for (int r = 0; r < 4; r++) mx[r] = fmaxf(mx[r], __shfl_xor(mx[r], m, 64));

        float sum[4] = {0.f, 0.f, 0.f, 0.f};
#pragma unroll
        for (int nt = 0; nt < 13; nt++)
#pragma unroll
            for (int r = 0; r < 4; r++) {
                float p = exp2f((s[nt][r] - mx[r]) * 0.18033688011112042f);
                s[nt][r] = p;
                sum[r] += p;
            }
#pragma unroll
        for (int m = 1; m < 16; m <<= 1)
#pragma unroll
            for (int r = 0; r < 4; r++) sum[r] += __shfl_xor(sum[r], m, 64);

#pragma unroll
        for (int nt = 0; nt < 13; nt++)
#pragma unroll
            for (int r = 0; r < 4; r++)
                myP[(quad * 4 + r) * 232 + nt * 16 + l15] = (f16)s[nt][r];

        f32x4 o[4];
#pragma unroll
        for (int n2 = 0; n2 < 4; n2++) { o[n2][0] = 0.f; o[n2][1] = 0.f; o[n2][2] = 0.f; o[n2][3] = 0.f; }
#pragma unroll
        for (int kc = 0; kc < 7; kc++) {
            f16x8 pa = *(const f16x8*)(&myP[l15 * 232 + kc * 32 + quad * 8]);
#pragma unroll
            for (int n2 = 0; n2 < 4; n2++) {
                f16x8 vb = *(const f16x8*)(&Vt[(n2 * 16 + l15) * 232 + kc * 32 + quad * 8]);
                o[n2] = __builtin_amdgcn_mfma_f32_16x16x32_f16(pa, vb, o[n2], 0, 0, 0);
            }
        }

        float inv[4];
#pragma unroll
        for (int r = 0; r < 4; r++) inv[r] = 1.f / sum[r];
#pragma unroll
        for (int n2 = 0; n2 < 4; n2++)
#pragma unroll
            for (int r = 0; r < 4; r++) {
                int m = qt * 16 + quad * 4 + r;
                if (m < PP)
                    ctx[(bb + 1 + (u64)t * PP + m) * DM + h * 64 + n2 * 16 + l15] = (f16)(o[n2][r] * inv[r]);
            }
    }
}

// ---------------- host ----------------
extern "C" void kernel_launch(void* const* d_in, const int* in_sizes, int n_in,
                              void* d_out, int out_size, void* d_ws, size_t ws_size,
                              hipStream_t stream) {
    const float* x_in  = (const float*)d_in[0];
    const float* t_Wq  = (const float*)d_in[1];
    const float* t_bq  = (const float*)d_in[2];
    const float* t_Wk  = (const float*)d_in[3];
    const float* t_bk  = (const float*)d_in[4];
    const float* t_Wv  = (const float*)d_in[5];
    const float* t_bv  = (const float*)d_in[6];
    const float* t_Wo  = (const float*)d_in[7];
    const float* t_bo  = (const float*)d_in[8];
    const float* s_Wq  = (const float*)d_in[9];
    const float* s_bq  = (const float*)d_in[10];
    const float* s_Wk  = (const float*)d_in[11];
    const float* s_bk  = (const float*)d_in[12];
    const float* s_Wv  = (const float*)d_in[13];
    const float* s_bv  = (const float*)d_in[14];
    const float* s_Wo  = (const float*)d_in[15];
    const float* s_bo  = (const float*)d_in[16];
    const float* W1    = (const float*)d_in[17];
    const float* b1    = (const float*)d_in[18];
    const float* W2    = (const float*)d_in[19];
    const float* b2    = (const float*)d_in[20];
    const float* ln1g  = (const float*)d_in[21];
    const float* ln1b  = (const float*)d_in[22];
    const float* ln2g  = (const float*)d_in[23];
    const float* ln2b  = (const float*)d_in[24];
    const float* ln3g  = (const float*)d_in[25];
    const float* ln3b  = (const float*)d_in[26];

    char* ws = (char*)d_ws;
    f16* y    = (f16*)(ws + Y_OFF);
    f16* qkv  = (f16*)(ws + QKV_OFF);
    f16* ctx  = (f16*)(ws + CTX_OFF);
    f16* hbuf = (f16*)(ws + H_OFF);
    float* clsP = (float*)(ws + Y_OFF);   // reuses dead y region
    char* wreg = ws + W_OFF;
    f16* tQKV  = (f16*)(wreg);
    f16* tWoT  = (f16*)(wreg + 3538944);
    f16* sQKV  = (f16*)(wreg + 4718592);
    f16* sWoT  = (f16*)(wreg + 8257536);
    f16* W1T   = (f16*)(wreg + 9437184);
    f16* W2T   = (f16*)(wreg + 14155776);
    float* tBias = (float*)(wreg + 18874368);
    float* sBias = (float*)(wreg + 18883584);
    float* xcur  = (float*)d_out;

    dim3 tb(256);
    // --- weight prep ---
    transpose_kernel<<<dim3(24, 24), tb, 0, stream>>>(t_Wq, tQKV, 768, 768);
    transpose_kernel<<<dim3(24, 24), tb, 0, stream>>>(t_Wk, tQKV + 768 * 768, 768, 768);
    transpose_kernel<<<dim3(24, 24), tb, 0, stream>>>(t_Wv, tQKV + 2 * 768 * 768, 768, 768);
    transpose_kernel<<<dim3(24, 24), tb, 0, stream>>>(t_Wo, tWoT, 768, 768);
    transpose_kernel<<<dim3(24, 24), tb, 0, stream>>>(s_Wq, sQKV, 768, 768);
    transpose_kernel<<<dim3(24, 24), tb, 0, stream>>>(s_Wk, sQKV + 768 * 768, 768, 768);
    transpose_kernel<<<dim3(24, 24), tb, 0, stream>>>(s_Wv, sQKV + 2 * 768 * 768, 768, 768);
    transpose_kernel<<<dim3(24, 24), tb, 0, stream>>>(s_Wo, sWoT, 768, 768);
    transpose_kernel<<<dim3(96, 24), tb, 0, stream>>>(W1, W1T, 768, 3072);
    transpose_kernel<<<dim3(24, 96), tb, 0, stream>>>(W2, W2T, 3072, 768);
    bias3_kernel<<<3, tb, 0, stream>>>(t_bq, t_bk, t_bv, tBias);
    bias3_kernel<<<3, tb, 0, stream>>>(s_bq, s_bk, s_bv, sBias);

    // --- phase A: time MHA ---
    ln_kernel<<<3138, tb, 0, stream>>>(x_in, ln1g, ln1b, y);
    gemm_kernel<QKVN, false, false, true><<<MB_PAD * 18, tb, 0, stream>>>(y, tQKV, tBias, nullptr, nullptr, qkv, 768);
    time_attn_kernel<<<4704, tb, 0, stream>>>(qkv, ctx);
    cls_part_kernel<<<BQ * NH * CCH, tb, 0, stream>>>(qkv, clsP);
    cls_comb_kernel<<<24, tb, 0, stream>>>(clsP, ctx);
    gemm_kernel<DM, false, true, false><<<MB_PAD * 6, tb, 0, stream>>>(ctx, tWoT, t_bo, x_in, xcur, nullptr, 768);

    // --- phase B: space MHA ---
    ln_kernel<<<3138, tb, 0, stream>>>(xcur, ln2g, ln2b, y);
    gemm_kernel<QKVN, false, false, true><<<MB_PAD * 18, tb, 0, stream>>>(y, sQKV, sBias, nullptr, nullptr, qkv, 768);
    space_attn_kernel<<<768, tb, 0, stream>>>(qkv, ctx);
    cls_part_kernel<<<BQ * NH * CCH, tb, 0, stream>>>(qkv, clsP);
    cls_comb_kernel<<<24, tb, 0, stream>>>(clsP, ctx);
    gemm_kernel<DM, false, true, false><<<MB_PAD * 6, tb, 0, stream>>>(ctx, sWoT, s_bo, xcur, xcur, nullptr, 768);

    // --- phase C: MLP ---
    ln_kernel<<<3138, tb, 0, stream>>>(xcur, ln3g, ln3b, y);
    gemm_kernel<D4, true, false, true><<<MB_PAD * 24, tb, 0, stream>>>(y, W1T, b1, nullptr, nullptr, hbuf, 768);
    gemm_kernel<DM, false, true, false><<<MB_PAD * 6, tb, 0, stream>>>(hbuf, W2T, b2, xcur, xcur, nullptr, 3072);
}